// Round 1
// 6300.385 us; speedup vs baseline: 1.5825x; 1.5825x over previous
//
#include <hip/hip_runtime.h>
#include <math.h>

#define NLAYERS 6

typedef unsigned short u16;
typedef unsigned int u32;
typedef __attribute__((ext_vector_type(4))) float floatx4;
typedef __attribute__((ext_vector_type(8))) short bf16x8;

__device__ __forceinline__ float silu_f(float x) { return x / (1.0f + __expf(-x)); }

__device__ __forceinline__ u16 f2b(float f) {
    union { float f; u32 u; } x; x.f = f;
    u32 r = x.u + 0x7fffu + ((x.u >> 16) & 1u);
    return (u16)(r >> 16);
}
__device__ __forceinline__ float b2f(u16 u) {
    union { u32 u; float f; } x; x.u = ((u32)u) << 16;
    return x.f;
}

__device__ __forceinline__ void gload_lds16(const void* g, void* l) {
    __builtin_amdgcn_global_load_lds((const __attribute__((address_space(1))) u32*)g,
                                     (__attribute__((address_space(3))) u32*)l, 16, 0, 0);
}

// stage a 128-row x 32-col bf16 tile (row-major [128][32]) from global (row stride ldk) into LDS
__device__ __forceinline__ void stage128x32(const u16* __restrict__ src, int ldk, short* lds, int t) {
    int w = t >> 6;
#pragma unroll
    for (int rep = 0; rep < 2; rep++) {
        int s = rep * 256 + t;
        int row = s >> 2, kp = s & 3;
        const u16* g = src + (size_t)row * ldk + kp * 8;
        short* lb = lds + (size_t)(rep * 256 + w * 64) * 8;  // wave-uniform base
        gload_lds16((const void*)g, (void*)lb);
    }
}

// ---------------- bf16 MFMA GEMM: C(MxN) = A(MxK) @ W(NxK)^T ----------------
// modes: accZ != null -> Z += gate * acc ; else outB != null -> bf16 store ; else outF = acc (+bias)
__global__ __launch_bounds__(256) void mfma_gemm_kernel(
    const u16* __restrict__ A, const u16* __restrict__ W, int M, int N, int K,
    float* __restrict__ outF, u16* __restrict__ outB, const float* __restrict__ bias,
    float* __restrict__ accZ, const float* __restrict__ gate, int gateStride) {
    __shared__ __align__(16) short As[128 * 32];
    __shared__ __align__(16) short Bs[128 * 32];
    int t = threadIdx.x;
    int lane = t & 63, wave = t >> 6;
    int wm = wave >> 1, wn = wave & 1;
    int m0 = blockIdx.y << 7, n0 = blockIdx.x << 7;
    int lm = lane & 15, kg = lane >> 4;
    floatx4 zero4 = {0.f, 0.f, 0.f, 0.f};
    floatx4 acc[4][4];
#pragma unroll
    for (int i = 0; i < 4; i++)
#pragma unroll
        for (int j = 0; j < 4; j++) acc[i][j] = zero4;
    const u16* Arow = A + (size_t)m0 * K;
    const u16* Wrow = W + (size_t)n0 * K;
    int aoff[4], boff[4];
#pragma unroll
    for (int i = 0; i < 4; i++) {
        aoff[i] = (wm * 64 + i * 16 + lm) * 32 + kg * 8;
        boff[i] = (wn * 64 + i * 16 + lm) * 32 + kg * 8;
    }
    for (int k0 = 0; k0 < K; k0 += 32) {
        stage128x32(Arow + k0, K, As, t);
        stage128x32(Wrow + k0, K, Bs, t);
        __syncthreads();
        bf16x8 af[4], bfr[4];
#pragma unroll
        for (int i = 0; i < 4; i++) af[i] = *(const bf16x8*)&As[aoff[i]];
#pragma unroll
        for (int j = 0; j < 4; j++) bfr[j] = *(const bf16x8*)&Bs[boff[j]];
#pragma unroll
        for (int i = 0; i < 4; i++)
#pragma unroll
            for (int j = 0; j < 4; j++)
                acc[i][j] = __builtin_amdgcn_mfma_f32_16x16x32_bf16(af[i], bfr[j], acc[i][j], 0, 0, 0);
        __syncthreads();
    }
#pragma unroll
    for (int i = 0; i < 4; i++) {
        int rbase = m0 + wm * 64 + i * 16 + kg * 4;
#pragma unroll
        for (int j = 0; j < 4; j++) {
            int c = n0 + wn * 64 + j * 16 + lm;
#pragma unroll
            for (int r = 0; r < 4; r++) {
                float v = acc[i][j][r];
                int row = rbase + r;
                size_t off = (size_t)row * N + c;
                if (accZ) {
                    accZ[off] += gate[(row >> 10) * gateStride + c] * v;
                } else if (outB) {
                    outB[off] = f2b(v);
                } else {
                    if (bias) v += bias[c];
                    outF[off] = v;
                }
            }
        }
    }
}

// ---------------- fused w1/w3 + swiglu: out = bf16( silu(A@W1^T) * (A@W3^T) ) ----------------
__global__ __launch_bounds__(256) void mfma_gemm_swiglu_kernel(
    const u16* __restrict__ A, const u16* __restrict__ W1, const u16* __restrict__ W3,
    int M, int N, int K, u16* __restrict__ outB) {
    __shared__ __align__(16) short As[128 * 32];
    __shared__ __align__(16) short B1s[128 * 32];
    __shared__ __align__(16) short B3s[128 * 32];
    int t = threadIdx.x;
    int lane = t & 63, wave = t >> 6;
    int wm = wave >> 1, wn = wave & 1;
    int m0 = blockIdx.y << 7, n0 = blockIdx.x << 7;
    int lm = lane & 15, kg = lane >> 4;
    floatx4 zero4 = {0.f, 0.f, 0.f, 0.f};
    floatx4 acc1[4][4], acc3[4][4];
#pragma unroll
    for (int i = 0; i < 4; i++)
#pragma unroll
        for (int j = 0; j < 4; j++) { acc1[i][j] = zero4; acc3[i][j] = zero4; }
    const u16* Arow = A + (size_t)m0 * K;
    const u16* W1row = W1 + (size_t)n0 * K;
    const u16* W3row = W3 + (size_t)n0 * K;
    int aoff[4], boff[4];
#pragma unroll
    for (int i = 0; i < 4; i++) {
        aoff[i] = (wm * 64 + i * 16 + lm) * 32 + kg * 8;
        boff[i] = (wn * 64 + i * 16 + lm) * 32 + kg * 8;
    }
    for (int k0 = 0; k0 < K; k0 += 32) {
        stage128x32(Arow + k0, K, As, t);
        stage128x32(W1row + k0, K, B1s, t);
        stage128x32(W3row + k0, K, B3s, t);
        __syncthreads();
        bf16x8 af[4], b1[4], b3[4];
#pragma unroll
        for (int i = 0; i < 4; i++) af[i] = *(const bf16x8*)&As[aoff[i]];
#pragma unroll
        for (int j = 0; j < 4; j++) { b1[j] = *(const bf16x8*)&B1s[boff[j]]; b3[j] = *(const bf16x8*)&B3s[boff[j]]; }
#pragma unroll
        for (int i = 0; i < 4; i++)
#pragma unroll
            for (int j = 0; j < 4; j++) {
                acc1[i][j] = __builtin_amdgcn_mfma_f32_16x16x32_bf16(af[i], b1[j], acc1[i][j], 0, 0, 0);
                acc3[i][j] = __builtin_amdgcn_mfma_f32_16x16x32_bf16(af[i], b3[j], acc3[i][j], 0, 0, 0);
            }
        __syncthreads();
    }
#pragma unroll
    for (int i = 0; i < 4; i++) {
        int rbase = m0 + wm * 64 + i * 16 + kg * 4;
#pragma unroll
        for (int j = 0; j < 4; j++) {
            int c = n0 + wn * 64 + j * 16 + lm;
#pragma unroll
            for (int r = 0; r < 4; r++) {
                int row = rbase + r;
                float v = silu_f(acc1[i][j][r]) * acc3[i][j][r];
                outB[(size_t)row * N + c] = f2b(v);
            }
        }
    }
}

// ---------------- fp32 -> bf16 conversion (up to 4 equal-size arrays) ----------------
__global__ void f2bN_kernel(const float* __restrict__ p0, const float* __restrict__ p1,
                            const float* __restrict__ p2, const float* __restrict__ p3,
                            u16* __restrict__ out, int n4each, int nptr) {
    int idx = blockIdx.x * 256 + threadIdx.x;
    if (idx >= n4each * nptr) return;
    int which = idx / n4each;
    int i = idx - which * n4each;
    const float* p = (which == 0) ? p0 : (which == 1) ? p1 : (which == 2) ? p2 : p3;
    float4 v = ((const float4*)p)[i];
    ushort4 o;
    o.x = f2b(v.x); o.y = f2b(v.y); o.z = f2b(v.z); o.w = f2b(v.w);
    ((ushort4*)out)[idx] = o;
}

// ---------------- temb ----------------
__global__ void temb1_kernel(const float* __restrict__ t, const float* __restrict__ w,
                             const float* __restrict__ b, float* __restrict__ out) {
    int idx = blockIdx.x * 256 + threadIdx.x;
    int bb = idx >> 10, n = idx & 1023;
    out[idx] = silu_f(t[bb] * w[n] + b[n]);
}

__global__ __launch_bounds__(256) void temb2_kernel(const float* __restrict__ A, const float* __restrict__ W,
                                                    const float* __restrict__ b2, const float* __restrict__ yemb,
                                                    const int* __restrict__ y, float* __restrict__ out) {
    int wid = blockIdx.x * 4 + (threadIdx.x >> 6);
    int lane = threadIdx.x & 63;
    int bb = wid >> 10, n = wid & 1023;
    const float* a = A + (bb << 10);
    const float* w = W + (n << 10);
    float s = 0.f;
    for (int k = lane << 2; k < 1024; k += 256) {
        float4 av = *(const float4*)&a[k];
        float4 wv = *(const float4*)&w[k];
        s += av.x * wv.x + av.y * wv.y + av.z * wv.z + av.w * wv.w;
    }
#pragma unroll
    for (int off = 32; off > 0; off >>= 1) s += __shfl_xor(s, off);
    if (lane == 0) {
        float vv = s + b2[n] + yemb[(size_t)y[bb] * 1024 + n];
        out[wid] = silu_f(vv);
    }
}

// ---------------- conv1: 4 -> 512, 5x5 SAME ----------------
__global__ __launch_bounds__(256) void conv1_kernel(const float* __restrict__ x, const float* __restrict__ w,
                                                    const float* __restrict__ bias, float* __restrict__ out) {
    int idx = blockIdx.x * 256 + threadIdx.x;
    int px = idx & 63;
    int py = (idx >> 6) & 63;
    int oc = (idx >> 12) & 511;
    int b = idx >> 21;
    float acc = bias[oc];
    for (int ic = 0; ic < 4; ic++) {
        const float* xp = x + (((b << 2) + ic) << 12);
        const float* wp = w + (oc * 4 + ic) * 25;
#pragma unroll
        for (int ky = 0; ky < 5; ky++) {
            int iy = py + ky - 2;
            if (iy < 0 || iy > 63) continue;
#pragma unroll
            for (int kx = 0; kx < 5; kx++) {
                int ix = px + kx - 2;
                if (ix < 0 || ix > 63) continue;
                acc += xp[(iy << 6) + ix] * wp[ky * 5 + kx];
            }
        }
    }
    out[idx] = acc;
}

// ---------------- fused silu + groupnorm ----------------
__global__ __launch_bounds__(256) void silu_gn_kernel(const float* __restrict__ in, float* __restrict__ out,
                                                      const float* __restrict__ g, const float* __restrict__ bt) {
    int blk = blockIdx.x;
    int b = blk >> 5, grp = blk & 31, c0 = grp << 4;
    const float* p = in + (size_t)((b * 512 + c0)) * 4096;
    float* q = out + (size_t)((b * 512 + c0)) * 4096;
    int t = threadIdx.x;
    float s = 0.f, sq = 0.f;
    for (int i = t; i < 16384; i += 256) {
        float4 v = ((const float4*)p)[i];
        float a0 = silu_f(v.x), a1 = silu_f(v.y), a2 = silu_f(v.z), a3 = silu_f(v.w);
        s += a0 + a1 + a2 + a3;
        sq += a0 * a0 + a1 * a1 + a2 * a2 + a3 * a3;
    }
    __shared__ float2 red[256];
    red[t] = make_float2(s, sq);
    __syncthreads();
    for (int st = 128; st > 0; st >>= 1) {
        if (t < st) { red[t].x += red[t + st].x; red[t].y += red[t + st].y; }
        __syncthreads();
    }
    float mean = red[0].x * (1.f / 65536.f);
    float var = red[0].y * (1.f / 65536.f) - mean * mean;
    float rstd = rsqrtf(var + 1e-5f);
    for (int i = t; i < 16384; i += 256) {
        float4 v = ((const float4*)p)[i];
        int ch = c0 + (i >> 10);
        float gg = g[ch], bb = bt[ch];
        float4 o;
        o.x = (silu_f(v.x) - mean) * rstd * gg + bb;
        o.y = (silu_f(v.y) - mean) * rstd * gg + bb;
        o.z = (silu_f(v.z) - mean) * rstd * gg + bb;
        o.w = (silu_f(v.w) - mean) * rstd * gg + bb;
        ((float4*)q)[i] = o;
    }
}

// ---------------- NCHW fp32 -> padded NHWC bf16 (B,68,68,512), interior only ----------------
__global__ __launch_bounds__(256) void nchw2nhwc_pad_kernel(const float* __restrict__ in, u16* __restrict__ out) {
    int blk = blockIdx.x;  // 4096 = b(4) * y(64) * ct(16)
    int ct = blk & 15;
    int yy = (blk >> 4) & 63;
    int b = blk >> 10;
    __shared__ float tile[32][65];
    int t = threadIdx.x;
    const float* ip = in + (((size_t)(b * 512 + (ct << 5))) << 12) + (yy << 6);
    for (int i = t; i < 2048; i += 256) {
        int cl = i >> 6, x = i & 63;
        tile[cl][x] = ip[((size_t)cl << 12) + x];
    }
    __syncthreads();
    u16* op = out + ((size_t)((b * 68 + yy + 2) * 68 + 2)) * 512 + (ct << 5);
    for (int i = t; i < 2048; i += 256) {
        int x = i >> 5, cl = i & 31;
        op[(size_t)x * 512 + cl] = f2b(tile[cl][x]);
    }
}

// ---------------- conv2_w (oc,ic,5,5) fp32 -> 25 tap-major (oc,ic) bf16 matrices ----------------
__global__ __launch_bounds__(256) void wtrans25_kernel(const float* __restrict__ w, u16* __restrict__ wt) {
    int idx = blockIdx.x * 256 + threadIdx.x;  // 262144 = oc*512 + ic
    const float* p = w + (size_t)idx * 25;
#pragma unroll
    for (int tap = 0; tap < 25; tap++)
        wt[(size_t)tap * 262144 + idx] = f2b(p[tap]);
}

// ---------------- conv2 as implicit GEMM via MFMA ----------------
// A = weights (M=512 oc), B = pixels (128/block), K = 25 taps x 512 ic
// Ipad: (B,68,68,512) bf16 zero-padded NHWC; Wt: (25,512,512) [tap][oc][ic] bf16
// out: (B,512,64,64) fp32 NCHW (+bias)
__global__ __launch_bounds__(256) void conv2_mfma_kernel(
    const u16* __restrict__ Ipad, const u16* __restrict__ Wt,
    const float* __restrict__ bias, float* __restrict__ out) {
    __shared__ __align__(16) short As[128 * 32];
    __shared__ __align__(16) short Bs[128 * 32];
    int t = threadIdx.x;
    int lane = t & 63, wave = t >> 6;
    int wm = wave >> 1, wn = wave & 1;
    int m0 = blockIdx.y << 7;          // oc tile base (0..511 step 128)
    int b = blockIdx.x >> 5;           // batch
    int y0 = (blockIdx.x & 31) << 1;   // output row pair
    int lm = lane & 15, kg = lane >> 4;
    floatx4 zero4 = {0.f, 0.f, 0.f, 0.f};
    floatx4 acc[4][4];
#pragma unroll
    for (int i = 0; i < 4; i++)
#pragma unroll
        for (int j = 0; j < 4; j++) acc[i][j] = zero4;
    int aoff[4], boff[4];
#pragma unroll
    for (int i = 0; i < 4; i++) {
        aoff[i] = (wm * 64 + i * 16 + lm) * 32 + kg * 8;
        boff[i] = (wn * 64 + i * 16 + lm) * 32 + kg * 8;
    }
    // staging decomposition for the pixel (B) tile: s = rep*256 + t
    int s0 = t, s1 = 256 + t;
    int row0 = s0 >> 2, kp0 = s0 & 3;
    int row1 = s1 >> 2, kp1 = s1 & 3;
    int po0 = (row0 >> 6) * 68 + (row0 & 63);   // padded-pixel offset for this lane's row
    int po1 = (row1 >> 6) * 68 + (row1 & 63);
    short* lb0 = Bs + (size_t)(wave * 64) * 8;         // wave-uniform LDS bases
    short* lb1 = Bs + (size_t)(256 + wave * 64) * 8;
    const u16* ibase = Ipad + ((size_t)(b * 68 + y0) * 68) * 512;
    int tap = 0;
    for (int ky = 0; ky < 5; ky++) {
        for (int kx = 0; kx < 5; kx++, tap++) {
            const u16* wsrc = Wt + (size_t)tap * 262144 + (size_t)m0 * 512;
            const u16* isrc = ibase + (size_t)(ky * 68 + kx) * 512;
            const u16* g0 = isrc + (size_t)po0 * 512 + kp0 * 8;
            const u16* g1 = isrc + (size_t)po1 * 512 + kp1 * 8;
            for (int k0 = 0; k0 < 512; k0 += 32) {
                stage128x32(wsrc + k0, 512, As, t);
                gload_lds16((const void*)(g0 + k0), (void*)lb0);
                gload_lds16((const void*)(g1 + k0), (void*)lb1);
                __syncthreads();
                bf16x8 af[4], bfr[4];
#pragma unroll
                for (int i = 0; i < 4; i++) af[i] = *(const bf16x8*)&As[aoff[i]];
#pragma unroll
                for (int j = 0; j < 4; j++) bfr[j] = *(const bf16x8*)&Bs[boff[j]];
#pragma unroll
                for (int i = 0; i < 4; i++)
#pragma unroll
                    for (int j = 0; j < 4; j++)
                        acc[i][j] = __builtin_amdgcn_mfma_f32_16x16x32_bf16(af[i], bfr[j], acc[i][j], 0, 0, 0);
                __syncthreads();
            }
        }
    }
#pragma unroll
    for (int i = 0; i < 4; i++) {
        int ocbase = m0 + wm * 64 + i * 16 + kg * 4;
#pragma unroll
        for (int j = 0; j < 4; j++) {
            int c = wn * 64 + j * 16 + lm;  // pixel index within tile (0..127)
            int py = y0 + (c >> 6), px = c & 63;
#pragma unroll
            for (int r = 0; r < 4; r++) {
                int oc = ocbase + r;
                out[((size_t)(b * 512 + oc) << 12) + (py << 6) + px] = acc[i][j][r] + bias[oc];
            }
        }
    }
}

// ---------------- patchify (B,512,64,64) f32 -> (B,1024,2048) bf16 ----------------
__global__ void patchify_kernel(const float* __restrict__ hn, u16* __restrict__ pout) {
    int idx = blockIdx.x * 256 + threadIdx.x;
    int kf = idx & 2047;
    int tk = (idx >> 11) & 1023;
    int b = idx >> 21;
    int c = kf >> 2;
    int a = (kf >> 1) & 1;
    int b2 = kf & 1;
    int ph = tk >> 5, pw = tk & 31;
    pout[idx] = f2b(hn[(size_t)((b * 512 + c)) * 4096 + (((ph << 1) + a) << 6) + (pw << 1) + b2]);
}

// ---------------- layernorm + modulate (fp32 in, fp32 or bf16 out) ----------------
template <typename OT>
__global__ __launch_bounds__(256) void ln_mod_kernel(const float* __restrict__ in, OT* __restrict__ out,
                                                     const float* __restrict__ g, const float* __restrict__ bt,
                                                     const float* __restrict__ shiftb, const float* __restrict__ scaleb,
                                                     int modStride, float eps) {
    int row = blockIdx.x;
    int b = row >> 10;
    int t = threadIdx.x;
    const float* p = in + ((size_t)row << 10);
    float4 x = ((const float4*)p)[t];
    float s = x.x + x.y + x.z + x.w;
    float sq = x.x * x.x + x.y * x.y + x.z * x.z + x.w * x.w;
    __shared__ float2 red[256];
    red[t] = make_float2(s, sq);
    __syncthreads();
    for (int st = 128; st > 0; st >>= 1) {
        if (t < st) { red[t].x += red[t + st].x; red[t].y += red[t + st].y; }
        __syncthreads();
    }
    float mean = red[0].x * (1.f / 1024.f);
    float var = red[0].y * (1.f / 1024.f) - mean * mean;
    float rstd = rsqrtf(var + eps);
    const float* sh = shiftb + b * modStride;
    const float* sc = scaleb + b * modStride;
    int c = t << 2;
    float o0, o1, o2, o3;
    {
        float xn = (x.x - mean) * rstd; if (g) xn = xn * g[c + 0] + bt[c + 0];
        o0 = xn * (1.f + sc[c + 0]) + sh[c + 0];
    }
    {
        float xn = (x.y - mean) * rstd; if (g) xn = xn * g[c + 1] + bt[c + 1];
        o1 = xn * (1.f + sc[c + 1]) + sh[c + 1];
    }
    {
        float xn = (x.z - mean) * rstd; if (g) xn = xn * g[c + 2] + bt[c + 2];
        o2 = xn * (1.f + sc[c + 2]) + sh[c + 2];
    }
    {
        float xn = (x.w - mean) * rstd; if (g) xn = xn * g[c + 3] + bt[c + 3];
        o3 = xn * (1.f + sc[c + 3]) + sh[c + 3];
    }
    if constexpr (sizeof(OT) == 4) {
        float4 o = make_float4(o0, o1, o2, o3);
        ((float4*)(out + ((size_t)row << 10)))[t] = o;
    } else {
        ushort4 o;
        o.x = f2b(o0); o.y = f2b(o1); o.z = f2b(o2); o.w = f2b(o3);
        ((ushort4*)(out + ((size_t)row << 10)))[t] = o;
    }
}

// ---------------- rope cos/sin table: (1024 positions x 32 freqs) float2 ----------------
__global__ void rope_table_kernel(float* __restrict__ RT) {
    int idx = blockIdx.x * 256 + threadIdx.x;  // 32768
    int j = idx & 31;
    int tt = idx >> 5;
    float inv = powf(10000.f, -(float)j * (1.f / 32.f));
    float ang = (float)tt * inv;
    ((float2*)RT)[idx] = make_float2(cosf(ang), sinf(ang));
}

// ---------------- rope (in-place, bf16 (B,T,H,D)) using precomputed table ----------------
__global__ void rope_kernel(u16* __restrict__ p, const float* __restrict__ RT) {
    int idx = blockIdx.x * 256 + threadIdx.x;  // 2097152
    int j = idx & 31;
    int tt = (idx >> 9) & 1023;
    float2 cssn = ((const float2*)RT)[(tt << 5) + j];
    float cs = cssn.x, sn = cssn.y;
    int h = (idx >> 5) & 15;
    int b = idx >> 19;
    size_t base = (size_t)(((b << 10) + tt)) * 1024 + (h << 6) + (j << 1);
    ushort2 v = *(ushort2*)&p[base];
    float x = b2f(v.x), yv = b2f(v.y);
    ushort2 o;
    o.x = f2b(x * cs - yv * sn);
    o.y = f2b(x * sn + yv * cs);
    *(ushort2*)&p[base] = o;
}

// ---------------- K transpose bf16: (B,T,H,D) -> (B,H,D,T) ----------------
__global__ void ktrans_kernel(const u16* __restrict__ k, u16* __restrict__ kT) {
    int idx = blockIdx.x * 256 + threadIdx.x;  // 4194304
    int s = idx & 1023;
    int d = (idx >> 10) & 63;
    int h = (idx >> 16) & 15;
    int b = idx >> 20;
    kT[idx] = k[(size_t)(((b << 10) + s)) * 1024 + (h << 6) + d];
}

// ---------------- fused attention, bf16 I/O, fp32 math ----------------
__global__ __launch_bounds__(256) void attn_kernel(const u16* __restrict__ q, const u16* __restrict__ kT,
                                                   const u16* __restrict__ v, u16* __restrict__ o) {
    int b = blockIdx.z, h = blockIdx.y, tq0 = blockIdx.x << 3;
    int t = threadIdx.x;
    __shared__ float qv[8][64];
    __shared__ float sc[8][1024];
    __shared__ float po[4][8][64];
    __shared__ float red[256];
    __shared__ float rowsum[8];
    for (int i = t; i < 512; i += 256) {
        int r = i >> 6, d = i & 63;
        qv[r][d] = b2f(q[(size_t)(((b << 10) + tq0 + r)) * 1024 + (h << 6) + d]);
    }
    __syncthreads();
    float4 acc4[8];
#pragma unroll
    for (int r = 0; r < 8; r++) acc4[r] = make_float4(0.f, 0.f, 0.f, 0.f);
    const u16* kTp = kT + (size_t)(((b << 4) + h) << 6) * 1024;
    for (int d = 0; d < 64; d++) {
        ushort4 ku = *(const ushort4*)&kTp[(d << 10) + (t << 2)];
        float k0 = b2f(ku.x), k1 = b2f(ku.y), k2 = b2f(ku.z), k3 = b2f(ku.w);
#pragma unroll
        for (int r = 0; r < 8; r++) {
            float qd = qv[r][d];
            acc4[r].x += k0 * qd; acc4[r].y += k1 * qd;
            acc4[r].z += k2 * qd; acc4[r].w += k3 * qd;
        }
    }
#pragma unroll
    for (int r = 0; r < 8; r++) {
        sc[r][(t << 2) + 0] = acc4[r].x * 0.125f;
        sc[r][(t << 2) + 1] = acc4[r].y * 0.125f;
        sc[r][(t << 2) + 2] = acc4[r].z * 0.125f;
        sc[r][(t << 2) + 3] = acc4[r].w * 0.125f;
    }
    __syncthreads();
    for (int r = 0; r < 8; r++) {
        float m = fmaxf(fmaxf(sc[r][(t << 2)], sc[r][(t << 2) + 1]),
                        fmaxf(sc[r][(t << 2) + 2], sc[r][(t << 2) + 3]));
        red[t] = m;
        __syncthreads();
        for (int st = 128; st > 0; st >>= 1) {
            if (t < st) red[t] = fmaxf(red[t], red[t + st]);
            __syncthreads();
        }
        float rmax = red[0];
        __syncthreads();
        float ssum = 0.f;
#pragma unroll
        for (int u = 0; u < 4; u++) {
            float e = __expf(sc[r][(t << 2) + u] - rmax);
            sc[r][(t << 2) + u] = e;
            ssum += e;
        }
        red[t] = ssum;
        __syncthreads();
        for (int st = 128; st > 0; st >>= 1) {
            if (t < st) red[t] += red[t + st];
            __syncthreads();
        }
        if (t == 0) rowsum[r] = red[0];
        __syncthreads();
    }
    int d = t & 63, c = t >> 6;
    float pacc[8];
#pragma unroll
    for (int r = 0; r < 8; r++) pacc[r] = 0.f;
    for (int i = 0; i < 256; i++) {
        int s = (c << 8) + i;
        float vv = b2f(v[(size_t)(((b << 10) + s)) * 1024 + (h << 6) + d]);
#pragma unroll
        for (int r = 0; r < 8; r++) pacc[r] += sc[r][s] * vv;
    }
#pragma unroll
    for (int r = 0; r < 8; r++) po[c][r][d] = pacc[r];
    __syncthreads();
    for (int i = t; i < 512; i += 256) {
        int r = i >> 6, dd = i & 63;
        float oo = (po[0][r][dd] + po[1][r][dd] + po[2][r][dd] + po[3][r][dd]) / rowsum[r];
        o[(size_t)(((b << 10) + tq0 + r)) * 1024 + (h << 6) + dd] = f2b(oo);
    }
}

// ---------------- small row-vector GEMM (fp32) ----------------
__global__ __launch_bounds__(256) void rowvec_gemm_kernel(const float* __restrict__ A, const float* __restrict__ W,
                                                          const float* __restrict__ bias, float* __restrict__ out,
                                                          int N, int K) {
    int wid = blockIdx.x * 4 + (threadIdx.x >> 6);
    int lane = threadIdx.x & 63;
    int b = wid / N, n = wid - b * N;
    const float* a = A + (size_t)b * K;
    const float* w = W + (size_t)n * K;
    float s = 0.f;
    for (int k = lane << 2; k < K; k += 256) {
        float4 av = *(const float4*)&a[k];
        float4 wv = *(const float4*)&w[k];
        s += av.x * wv.x + av.y * wv.y + av.z * wv.z + av.w * wv.w;
    }
#pragma unroll
    for (int off = 32; off > 0; off >>= 1) s += __shfl_xor(s, off);
    if (lane == 0) out[wid] = s + (bias ? bias[n] : 0.f);
}

// ---------------- final projection: (4096x1024) @ (16x1024)^T + bias (fp32) ----------------
__global__ __launch_bounds__(256) void fin_gemm_kernel(const float* __restrict__ zf, const float* __restrict__ w,
                                                       const float* __restrict__ bias, float* __restrict__ out) {
    int idx = blockIdx.x * 256 + threadIdx.x;  // 65536
    int m = idx >> 4, n = idx & 15;
    const float* a = zf + ((size_t)m << 10);
    const float* wp = w + ((size_t)n << 10);
    float s = 0.f;
    for (int k = 0; k < 1024; k += 4) {
        float4 av = *(const float4*)&a[k];
        float4 wv = *(const float4*)&wp[k];
        s += av.x * wv.x + av.y * wv.y + av.z * wv.z + av.w * wv.w;
    }
    out[idx] = s + bias[n];
}

// ---------------- unpatchify -> (B,4,64,64) ----------------
__global__ void unpatch_kernel(const float* __restrict__ ot, float* __restrict__ out) {
    int idx = blockIdx.x * 256 + threadIdx.x;  // 65536
    int x = idx & 63;
    int yy = (idx >> 6) & 63;
    int ci = (idx >> 12) & 3;
    int b = idx >> 14;
    out[idx] = ot[(size_t)(((b << 10) + ((yy >> 1) << 5) + (x >> 1))) * 16 + (((yy & 1) << 1) + (x & 1)) * 4 + ci];
}

// ---------------- host orchestration ----------------
extern "C" void kernel_launch(void* const* d_in, const int* in_sizes, int n_in,
                              void* d_out, int out_size, void* d_ws, size_t ws_size,
                              hipStream_t stream) {
    const float* x       = (const float*)d_in[0];
    const float* tin     = (const float*)d_in[1];
    const int*   y       = (const int*)d_in[2];
    const float* conv1_w = (const float*)d_in[3];
    const float* conv1_b = (const float*)d_in[4];
    const float* gn1_g   = (const float*)d_in[5];
    const float* gn1_b   = (const float*)d_in[6];
    const float* conv2_w = (const float*)d_in[7];
    const float* conv2_b = (const float*)d_in[8];
    const float* gn2_g   = (const float*)d_in[9];
    const float* gn2_b   = (const float*)d_in[10];
    const float* xemb_w  = (const float*)d_in[11];
    const float* xemb_b  = (const float*)d_in[12];
    const float* t1_w    = (const float*)d_in[13];
    const float* t1_b    = (const float*)d_in[14];
    const float* t2_w    = (const float*)d_in[15];
    const float* t2_b    = (const float*)d_in[16];
    const float* y_emb   = (const float*)d_in[17];
    const float* wq      = (const float*)d_in[18];
    const float* wk      = (const float*)d_in[19];
    const float* wv      = (const float*)d_in[20];
    const float* wo      = (const float*)d_in[21];
    const float* w1      = (const float*)d_in[22];
    const float* w3      = (const float*)d_in[23];   // dict order: w1, w3, w2
    const float* w2      = (const float*)d_in[24];
    const float* ada_w   = (const float*)d_in[25];
    const float* ada_b   = (const float*)d_in[26];
    const float* an_g    = (const float*)d_in[27];
    const float* an_b    = (const float*)d_in[28];
    const float* fn_g    = (const float*)d_in[29];
    const float* fn_b    = (const float*)d_in[30];
    const float* fin_ada_w = (const float*)d_in[31];
    const float* fin_ada_b = (const float*)d_in[32];
    const float* fin_w   = (const float*)d_in[33];
    const float* fin_b   = (const float*)d_in[34];

    char* wsb = (char*)d_ws;
    // byte layout (total ~112.5 MB)
    float* Z    = (float*)(wsb + 0);               // 16 MB residual stream (fp32)
    u16*  Wbf   = (u16*)(wsb + (16ull << 20));     // 18 MB per-layer bf16 weights
    u16*  HHb   = (u16*)(wsb + (34ull << 20));     // 8 MB ln/mod output bf16
    u16*  Qb    = (u16*)(wsb + (42ull << 20));     // 8 MB
    u16*  Kb    = (u16*)(wsb + (50ull << 20));     // 8 MB
    u16*  Vb    = (u16*)(wsb + (58ull << 20));     // 8 MB
    u16*  KTb   = (u16*)(wsb + (66ull << 20));     // 8 MB
    u16*  AOb   = (u16*)(wsb + (74ull << 20));     // 8 MB attn out bf16
    u16*  F1b   = (u16*)(wsb + (82ull << 20));     // 23.1 MB ff hidden bf16
    // stem-phase overlays (dead once the transformer starts)
    float* A0f  = (float*)(wsb + (42ull << 20));   // 33.6 MB
    float* A1f  = (float*)(wsb + (76ull << 20));   // 33.6 MB (ends ~109.6 MB)
    u16*  IPad  = (u16*)(wsb + 0);                 // 18.1 MB padded NHWC bf16 (overlays Z; dead before Z written)
    u16*  WTc   = (u16*)(wsb + (20ull << 20));     // 12.5 MB conv2 tap-major bf16 weights (overlays PATb tail)
    u16*  PATb  = (u16*)(wsb + (16ull << 20));     // 16.8 MB patches bf16
    u16*  XWb   = (u16*)(wsb + (34ull << 20));     // 4 MB xemb_w bf16
    float* ZF   = (float*)(wsb + (42ull << 20));   // final zf fp32 (over Qb/Kb)
    float* SM   = (float*)(wsb + (110ull << 20));  // small buffers
    float* TMB  = SM;            // 4096
    float* CSI  = TMB + 4096;    // 4096
    float* MODS = CSI + 4096;    // 24576
    float* FM   = MODS + 24576;  // 8192
    float* OT   = FM + 8192;     // 65536
    float* RT   = (float*)(wsb + (112ull << 20));  // 256 KB rope table

    // constant prep (no activation deps)
    hipMemsetAsync(IPad, 0, (size_t)4 * 68 * 68 * 512 * 2, stream);
    rope_table_kernel<<<128, 256, 0, stream>>>(RT);
    wtrans25_kernel<<<1024, 256, 0, stream>>>(conv2_w, WTc);

    // conditioning
    temb1_kernel<<<16, 256, 0, stream>>>(tin, t1_w, t1_b, TMB);
    temb2_kernel<<<1024, 256, 0, stream>>>(TMB, t2_w, t2_b, y_emb, y, CSI);

    // conv stem
    conv1_kernel<<<32768, 256, 0, stream>>>(x, conv1_w, conv1_b, A0f);
    silu_gn_kernel<<<128, 256, 0, stream>>>(A0f, A1f, gn1_g, gn1_b);
    nchw2nhwc_pad_kernel<<<4096, 256, 0, stream>>>(A1f, IPad);
    conv2_mfma_kernel<<<dim3(128, 4), 256, 0, stream>>>(IPad, WTc, conv2_b, A0f);
    silu_gn_kernel<<<128, 256, 0, stream>>>(A0f, A1f, gn2_g, gn2_b);
    patchify_kernel<<<32768, 256, 0, stream>>>(A1f, PATb);
    f2bN_kernel<<<2048, 256, 0, stream>>>(xemb_w, nullptr, nullptr, nullptr, XWb, 524288, 1);
    mfma_gemm_kernel<<<dim3(8, 32), 256, 0, stream>>>(PATb, XWb, 4096, 1024, 2048,
                                                      Z, nullptr, xemb_b, nullptr, nullptr, 0);

    for (int i = 0; i < NLAYERS; i++) {
        const float* wq_i = wq + (size_t)i * 1048576;
        const float* wk_i = wk + (size_t)i * 1048576;
        const float* wv_i = wv + (size_t)i * 1048576;
        const float* wo_i = wo + (size_t)i * 1048576;
        const float* w1_i = w1 + (size_t)i * 2883584;
        const float* w3_i = w3 + (size_t)i * 2883584;
        const float* w2_i = w2 + (size_t)i * 2883584;
        const float* ada_w_i = ada_w + (size_t)i * 6291456;
        const float* ada_b_i = ada_b + (size_t)i * 6144;

        // bf16 weights for attn part: [wq|wk|wv|wo]
        f2bN_kernel<<<4096, 256, 0, stream>>>(wq_i, wk_i, wv_i, wo_i, Wbf, 262144, 4);
        // adaLN mods (fp32)
        rowvec_gemm_kernel<<<6144, 256, 0, stream>>>(CSI, ada_w_i, ada_b_i, MODS, 6144, 1024);
        // attn branch
        ln_mod_kernel<u16><<<4096, 256, 0, stream>>>(Z, HHb, an_g + i * 1024, an_b + i * 1024,
                                                     MODS + 0, MODS + 1024, 6144, 1e-5f);
        mfma_gemm_kernel<<<dim3(8, 32), 256, 0, stream>>>(HHb, Wbf + 0ull, 4096, 1024, 1024,
                                                          nullptr, Qb, nullptr, nullptr, nullptr, 0);
        mfma_gemm_kernel<<<dim3(8, 32), 256, 0, stream>>>(HHb, Wbf + 1048576ull, 4096, 1024, 1024,
                                                          nullptr, Kb, nullptr, nullptr, nullptr, 0);
        mfma_gemm_kernel<<<dim3(8, 32), 256, 0, stream>>>(HHb, Wbf + 2097152ull, 4096, 1024, 1024,
                                                          nullptr, Vb, nullptr, nullptr, nullptr, 0);
        rope_kernel<<<8192, 256, 0, stream>>>(Qb, RT);
        rope_kernel<<<8192, 256, 0, stream>>>(Kb, RT);
        ktrans_kernel<<<16384, 256, 0, stream>>>(Kb, KTb);
        attn_kernel<<<dim3(128, 16, 4), 256, 0, stream>>>(Qb, KTb, Vb, AOb);
        mfma_gemm_kernel<<<dim3(8, 32), 256, 0, stream>>>(AOb, Wbf + 3145728ull, 4096, 1024, 1024,
                                                          nullptr, nullptr, nullptr, Z, MODS + 2048, 6144);
        // ff branch
        ln_mod_kernel<u16><<<4096, 256, 0, stream>>>(Z, HHb, fn_g + i * 1024, fn_b + i * 1024,
                                                     MODS + 3072, MODS + 4096, 6144, 1e-5f);
        f2bN_kernel<<<8448, 256, 0, stream>>>(w1_i, w3_i, w2_i, nullptr, Wbf, 720896, 3);
        mfma_gemm_swiglu_kernel<<<dim3(22, 32), 256, 0, stream>>>(HHb, Wbf, Wbf + 2883584ull,
                                                                  4096, 2816, 1024, F1b);
        mfma_gemm_kernel<<<dim3(8, 32), 256, 0, stream>>>(F1b, Wbf + 5767168ull, 4096, 1024, 2816,
                                                          nullptr, nullptr, nullptr, Z, MODS + 5120, 6144);
    }

    // final head
    rowvec_gemm_kernel<<<2048, 256, 0, stream>>>(CSI, fin_ada_w, fin_ada_b, FM, 2048, 1024);
    ln_mod_kernel<float><<<4096, 256, 0, stream>>>(Z, ZF, nullptr, nullptr, FM + 0, FM + 1024, 2048, 1e-6f);
    fin_gemm_kernel<<<256, 256, 0, stream>>>(ZF, fin_w, fin_b, OT);
    unpatch_kernel<<<256, 256, 0, stream>>>(OT, (float*)d_out);
}

// Round 2
// 3881.577 us; speedup vs baseline: 2.5686x; 1.6232x over previous
//
#include <hip/hip_runtime.h>
#include <math.h>

#define NLAYERS 6

typedef unsigned short u16;
typedef unsigned int u32;
typedef __attribute__((ext_vector_type(4))) float floatx4;
typedef __attribute__((ext_vector_type(8))) short bf16x8;

__device__ __forceinline__ float silu_f(float x) { return x / (1.0f + __expf(-x)); }

__device__ __forceinline__ u16 f2b(float f) {
    union { float f; u32 u; } x; x.f = f;
    u32 r = x.u + 0x7fffu + ((x.u >> 16) & 1u);
    return (u16)(r >> 16);
}
__device__ __forceinline__ float b2f(u16 u) {
    union { u32 u; float f; } x; x.u = ((u32)u) << 16;
    return x.f;
}

__device__ __forceinline__ void gload_lds16(const void* g, void* l) {
    __builtin_amdgcn_global_load_lds((const __attribute__((address_space(1))) u32*)g,
                                     (__attribute__((address_space(3))) u32*)l, 16, 0, 0);
}

// stage a 128-row x 32-col bf16 tile (row-major [128][32]) from global (row stride ldk) into LDS
__device__ __forceinline__ void stage128x32(const u16* __restrict__ src, int ldk, short* lds, int t) {
    int w = t >> 6;
#pragma unroll
    for (int rep = 0; rep < 2; rep++) {
        int s = rep * 256 + t;
        int row = s >> 2, kp = s & 3;
        const u16* g = src + (size_t)row * ldk + kp * 8;
        short* lb = lds + (size_t)(rep * 256 + w * 64) * 8;  // wave-uniform base
        gload_lds16((const void*)g, (void*)lb);
    }
}

// stage 128 rows x 64 cols bf16 from (row stride 1024) global into LDS [128][64],
// with source-chunk XOR swizzle: LDS[row][cc] = global[row][cc ^ (row&7)]
__device__ __forceinline__ void stage_attn128x64(const u16* __restrict__ base, short* lds, int t) {
    int w = t >> 6;
#pragma unroll
    for (int rep = 0; rep < 4; rep++) {
        int cid = rep * 256 + t;
        int row = cid >> 3, cc = cid & 7;
        int gcc = cc ^ (row & 7);
        const u16* g = base + (size_t)row * 1024 + gcc * 8;
        short* lb = lds + (size_t)(rep * 256 + w * 64) * 8;
        gload_lds16((const void*)g, (void*)lb);
    }
}

// stage 64 rows x 128 cols bf16 from (row stride 1024) global into LDS [64][128],
// swizzle on low 3 chunk bits: LDS[row][cc] = global[row][(cc&8)|((cc^row)&7)]
__device__ __forceinline__ void stage_attn64x128(const u16* __restrict__ base, short* lds, int t) {
    int w = t >> 6;
#pragma unroll
    for (int rep = 0; rep < 4; rep++) {
        int cid = rep * 256 + t;
        int row = cid >> 4, cc = cid & 15;
        int gcc = (cc & 8) | ((cc ^ row) & 7);
        const u16* g = base + (size_t)row * 1024 + gcc * 8;
        short* lb = lds + (size_t)(rep * 256 + w * 64) * 8;
        gload_lds16((const void*)g, (void*)lb);
    }
}

// ---------------- bf16 MFMA GEMM: C(MxN) = A(MxK) @ W(NxK)^T ----------------
// modes: accZ != null -> Z += gate * acc ; else outB != null -> bf16 store ; else outF = acc (+bias)
__global__ __launch_bounds__(256) void mfma_gemm_kernel(
    const u16* __restrict__ A, const u16* __restrict__ W, int M, int N, int K,
    float* __restrict__ outF, u16* __restrict__ outB, const float* __restrict__ bias,
    float* __restrict__ accZ, const float* __restrict__ gate, int gateStride) {
    __shared__ __align__(16) short As[128 * 32];
    __shared__ __align__(16) short Bs[128 * 32];
    int t = threadIdx.x;
    int lane = t & 63, wave = t >> 6;
    int wm = wave >> 1, wn = wave & 1;
    int m0 = blockIdx.y << 7, n0 = blockIdx.x << 7;
    int lm = lane & 15, kg = lane >> 4;
    floatx4 zero4 = {0.f, 0.f, 0.f, 0.f};
    floatx4 acc[4][4];
#pragma unroll
    for (int i = 0; i < 4; i++)
#pragma unroll
        for (int j = 0; j < 4; j++) acc[i][j] = zero4;
    const u16* Arow = A + (size_t)m0 * K;
    const u16* Wrow = W + (size_t)n0 * K;
    int aoff[4], boff[4];
#pragma unroll
    for (int i = 0; i < 4; i++) {
        aoff[i] = (wm * 64 + i * 16 + lm) * 32 + kg * 8;
        boff[i] = (wn * 64 + i * 16 + lm) * 32 + kg * 8;
    }
    for (int k0 = 0; k0 < K; k0 += 32) {
        stage128x32(Arow + k0, K, As, t);
        stage128x32(Wrow + k0, K, Bs, t);
        __syncthreads();
        bf16x8 af[4], bfr[4];
#pragma unroll
        for (int i = 0; i < 4; i++) af[i] = *(const bf16x8*)&As[aoff[i]];
#pragma unroll
        for (int j = 0; j < 4; j++) bfr[j] = *(const bf16x8*)&Bs[boff[j]];
#pragma unroll
        for (int i = 0; i < 4; i++)
#pragma unroll
            for (int j = 0; j < 4; j++)
                acc[i][j] = __builtin_amdgcn_mfma_f32_16x16x32_bf16(af[i], bfr[j], acc[i][j], 0, 0, 0);
        __syncthreads();
    }
#pragma unroll
    for (int i = 0; i < 4; i++) {
        int rbase = m0 + wm * 64 + i * 16 + kg * 4;
#pragma unroll
        for (int j = 0; j < 4; j++) {
            int c = n0 + wn * 64 + j * 16 + lm;
#pragma unroll
            for (int r = 0; r < 4; r++) {
                float v = acc[i][j][r];
                int row = rbase + r;
                size_t off = (size_t)row * N + c;
                if (accZ) {
                    accZ[off] += gate[(row >> 10) * gateStride + c] * v;
                } else if (outB) {
                    outB[off] = f2b(v);
                } else {
                    if (bias) v += bias[c];
                    outF[off] = v;
                }
            }
        }
    }
}

// ---------------- fused w1/w3 + swiglu: out = bf16( silu(A@W1^T) * (A@W3^T) ) ----------------
__global__ __launch_bounds__(256) void mfma_gemm_swiglu_kernel(
    const u16* __restrict__ A, const u16* __restrict__ W1, const u16* __restrict__ W3,
    int M, int N, int K, u16* __restrict__ outB) {
    __shared__ __align__(16) short As[128 * 32];
    __shared__ __align__(16) short B1s[128 * 32];
    __shared__ __align__(16) short B3s[128 * 32];
    int t = threadIdx.x;
    int lane = t & 63, wave = t >> 6;
    int wm = wave >> 1, wn = wave & 1;
    int m0 = blockIdx.y << 7, n0 = blockIdx.x << 7;
    int lm = lane & 15, kg = lane >> 4;
    floatx4 zero4 = {0.f, 0.f, 0.f, 0.f};
    floatx4 acc1[4][4], acc3[4][4];
#pragma unroll
    for (int i = 0; i < 4; i++)
#pragma unroll
        for (int j = 0; j < 4; j++) { acc1[i][j] = zero4; acc3[i][j] = zero4; }
    const u16* Arow = A + (size_t)m0 * K;
    const u16* W1row = W1 + (size_t)n0 * K;
    const u16* W3row = W3 + (size_t)n0 * K;
    int aoff[4], boff[4];
#pragma unroll
    for (int i = 0; i < 4; i++) {
        aoff[i] = (wm * 64 + i * 16 + lm) * 32 + kg * 8;
        boff[i] = (wn * 64 + i * 16 + lm) * 32 + kg * 8;
    }
    for (int k0 = 0; k0 < K; k0 += 32) {
        stage128x32(Arow + k0, K, As, t);
        stage128x32(W1row + k0, K, B1s, t);
        stage128x32(W3row + k0, K, B3s, t);
        __syncthreads();
        bf16x8 af[4], b1[4], b3[4];
#pragma unroll
        for (int i = 0; i < 4; i++) af[i] = *(const bf16x8*)&As[aoff[i]];
#pragma unroll
        for (int j = 0; j < 4; j++) { b1[j] = *(const bf16x8*)&B1s[boff[j]]; b3[j] = *(const bf16x8*)&B3s[boff[j]]; }
#pragma unroll
        for (int i = 0; i < 4; i++)
#pragma unroll
            for (int j = 0; j < 4; j++) {
                acc1[i][j] = __builtin_amdgcn_mfma_f32_16x16x32_bf16(af[i], b1[j], acc1[i][j], 0, 0, 0);
                acc3[i][j] = __builtin_amdgcn_mfma_f32_16x16x32_bf16(af[i], b3[j], acc3[i][j], 0, 0, 0);
            }
        __syncthreads();
    }
#pragma unroll
    for (int i = 0; i < 4; i++) {
        int rbase = m0 + wm * 64 + i * 16 + kg * 4;
#pragma unroll
        for (int j = 0; j < 4; j++) {
            int c = n0 + wn * 64 + j * 16 + lm;
#pragma unroll
            for (int r = 0; r < 4; r++) {
                int row = rbase + r;
                float v = silu_f(acc1[i][j][r]) * acc3[i][j][r];
                outB[(size_t)row * N + c] = f2b(v);
            }
        }
    }
}

// ---------------- fp32 -> bf16 conversion (up to 4 equal-size arrays) ----------------
__global__ void f2bN_kernel(const float* __restrict__ p0, const float* __restrict__ p1,
                            const float* __restrict__ p2, const float* __restrict__ p3,
                            u16* __restrict__ out, int n4each, int nptr) {
    int idx = blockIdx.x * 256 + threadIdx.x;
    if (idx >= n4each * nptr) return;
    int which = idx / n4each;
    int i = idx - which * n4each;
    const float* p = (which == 0) ? p0 : (which == 1) ? p1 : (which == 2) ? p2 : p3;
    float4 v = ((const float4*)p)[i];
    ushort4 o;
    o.x = f2b(v.x); o.y = f2b(v.y); o.z = f2b(v.z); o.w = f2b(v.w);
    ((ushort4*)out)[idx] = o;
}

// ---------------- temb ----------------
__global__ void temb1_kernel(const float* __restrict__ t, const float* __restrict__ w,
                             const float* __restrict__ b, float* __restrict__ out) {
    int idx = blockIdx.x * 256 + threadIdx.x;
    int bb = idx >> 10, n = idx & 1023;
    out[idx] = silu_f(t[bb] * w[n] + b[n]);
}

__global__ __launch_bounds__(256) void temb2_kernel(const float* __restrict__ A, const float* __restrict__ W,
                                                    const float* __restrict__ b2, const float* __restrict__ yemb,
                                                    const int* __restrict__ y, float* __restrict__ out) {
    int wid = blockIdx.x * 4 + (threadIdx.x >> 6);
    int lane = threadIdx.x & 63;
    int bb = wid >> 10, n = wid & 1023;
    const float* a = A + (bb << 10);
    const float* w = W + (n << 10);
    float s = 0.f;
    for (int k = lane << 2; k < 1024; k += 256) {
        float4 av = *(const float4*)&a[k];
        float4 wv = *(const float4*)&w[k];
        s += av.x * wv.x + av.y * wv.y + av.z * wv.z + av.w * wv.w;
    }
#pragma unroll
    for (int off = 32; off > 0; off >>= 1) s += __shfl_xor(s, off);
    if (lane == 0) {
        float vv = s + b2[n] + yemb[(size_t)y[bb] * 1024 + n];
        out[wid] = silu_f(vv);
    }
}

// ---------------- conv1: 4 -> 512, 5x5 SAME ----------------
__global__ __launch_bounds__(256) void conv1_kernel(const float* __restrict__ x, const float* __restrict__ w,
                                                    const float* __restrict__ bias, float* __restrict__ out) {
    int idx = blockIdx.x * 256 + threadIdx.x;
    int px = idx & 63;
    int py = (idx >> 6) & 63;
    int oc = (idx >> 12) & 511;
    int b = idx >> 21;
    float acc = bias[oc];
    for (int ic = 0; ic < 4; ic++) {
        const float* xp = x + (((b << 2) + ic) << 12);
        const float* wp = w + (oc * 4 + ic) * 25;
#pragma unroll
        for (int ky = 0; ky < 5; ky++) {
            int iy = py + ky - 2;
            if (iy < 0 || iy > 63) continue;
#pragma unroll
            for (int kx = 0; kx < 5; kx++) {
                int ix = px + kx - 2;
                if (ix < 0 || ix > 63) continue;
                acc += xp[(iy << 6) + ix] * wp[ky * 5 + kx];
            }
        }
    }
    out[idx] = acc;
}

// ---------------- fused silu + groupnorm ----------------
__global__ __launch_bounds__(256) void silu_gn_kernel(const float* __restrict__ in, float* __restrict__ out,
                                                      const float* __restrict__ g, const float* __restrict__ bt) {
    int blk = blockIdx.x;
    int b = blk >> 5, grp = blk & 31, c0 = grp << 4;
    const float* p = in + (size_t)((b * 512 + c0)) * 4096;
    float* q = out + (size_t)((b * 512 + c0)) * 4096;
    int t = threadIdx.x;
    float s = 0.f, sq = 0.f;
    for (int i = t; i < 16384; i += 256) {
        float4 v = ((const float4*)p)[i];
        float a0 = silu_f(v.x), a1 = silu_f(v.y), a2 = silu_f(v.z), a3 = silu_f(v.w);
        s += a0 + a1 + a2 + a3;
        sq += a0 * a0 + a1 * a1 + a2 * a2 + a3 * a3;
    }
    __shared__ float2 red[256];
    red[t] = make_float2(s, sq);
    __syncthreads();
    for (int st = 128; st > 0; st >>= 1) {
        if (t < st) { red[t].x += red[t + st].x; red[t].y += red[t + st].y; }
        __syncthreads();
    }
    float mean = red[0].x * (1.f / 65536.f);
    float var = red[0].y * (1.f / 65536.f) - mean * mean;
    float rstd = rsqrtf(var + 1e-5f);
    for (int i = t; i < 16384; i += 256) {
        float4 v = ((const float4*)p)[i];
        int ch = c0 + (i >> 10);
        float gg = g[ch], bb = bt[ch];
        float4 o;
        o.x = (silu_f(v.x) - mean) * rstd * gg + bb;
        o.y = (silu_f(v.y) - mean) * rstd * gg + bb;
        o.z = (silu_f(v.z) - mean) * rstd * gg + bb;
        o.w = (silu_f(v.w) - mean) * rstd * gg + bb;
        ((float4*)q)[i] = o;
    }
}

// ---------------- NCHW fp32 -> padded NHWC bf16 (B,68,68,512), interior only ----------------
__global__ __launch_bounds__(256) void nchw2nhwc_pad_kernel(const float* __restrict__ in, u16* __restrict__ out) {
    int blk = blockIdx.x;  // 4096 = b(4) * y(64) * ct(16)
    int ct = blk & 15;
    int yy = (blk >> 4) & 63;
    int b = blk >> 10;
    __shared__ float tile[32][65];
    int t = threadIdx.x;
    const float* ip = in + (((size_t)(b * 512 + (ct << 5))) << 12) + (yy << 6);
    for (int i = t; i < 2048; i += 256) {
        int cl = i >> 6, x = i & 63;
        tile[cl][x] = ip[((size_t)cl << 12) + x];
    }
    __syncthreads();
    u16* op = out + ((size_t)((b * 68 + yy + 2) * 68 + 2)) * 512 + (ct << 5);
    for (int i = t; i < 2048; i += 256) {
        int x = i >> 5, cl = i & 31;
        op[(size_t)x * 512 + cl] = f2b(tile[cl][x]);
    }
}

// ---------------- conv2_w (oc,ic,5,5) fp32 -> 25 tap-major (oc,ic) bf16 matrices ----------------
__global__ __launch_bounds__(256) void wtrans25_kernel(const float* __restrict__ w, u16* __restrict__ wt) {
    int idx = blockIdx.x * 256 + threadIdx.x;  // 262144 = oc*512 + ic
    const float* p = w + (size_t)idx * 25;
#pragma unroll
    for (int tap = 0; tap < 25; tap++)
        wt[(size_t)tap * 262144 + idx] = f2b(p[tap]);
}

// ---------------- conv2 as implicit GEMM via MFMA ----------------
__global__ __launch_bounds__(256) void conv2_mfma_kernel(
    const u16* __restrict__ Ipad, const u16* __restrict__ Wt,
    const float* __restrict__ bias, float* __restrict__ out) {
    __shared__ __align__(16) short As[128 * 32];
    __shared__ __align__(16) short Bs[128 * 32];
    int t = threadIdx.x;
    int lane = t & 63, wave = t >> 6;
    int wm = wave >> 1, wn = wave & 1;
    int m0 = blockIdx.y << 7;          // oc tile base (0..511 step 128)
    int b = blockIdx.x >> 5;           // batch
    int y0 = (blockIdx.x & 31) << 1;   // output row pair
    int lm = lane & 15, kg = lane >> 4;
    floatx4 zero4 = {0.f, 0.f, 0.f, 0.f};
    floatx4 acc[4][4];
#pragma unroll
    for (int i = 0; i < 4; i++)
#pragma unroll
        for (int j = 0; j < 4; j++) acc[i][j] = zero4;
    int aoff[4], boff[4];
#pragma unroll
    for (int i = 0; i < 4; i++) {
        aoff[i] = (wm * 64 + i * 16 + lm) * 32 + kg * 8;
        boff[i] = (wn * 64 + i * 16 + lm) * 32 + kg * 8;
    }
    int s0 = t, s1 = 256 + t;
    int row0 = s0 >> 2, kp0 = s0 & 3;
    int row1 = s1 >> 2, kp1 = s1 & 3;
    int po0 = (row0 >> 6) * 68 + (row0 & 63);
    int po1 = (row1 >> 6) * 68 + (row1 & 63);
    short* lb0 = Bs + (size_t)(wave * 64) * 8;
    short* lb1 = Bs + (size_t)(256 + wave * 64) * 8;
    const u16* ibase = Ipad + ((size_t)(b * 68 + y0) * 68) * 512;
    int tap = 0;
    for (int ky = 0; ky < 5; ky++) {
        for (int kx = 0; kx < 5; kx++, tap++) {
            const u16* wsrc = Wt + (size_t)tap * 262144 + (size_t)m0 * 512;
            const u16* isrc = ibase + (size_t)(ky * 68 + kx) * 512;
            const u16* g0 = isrc + (size_t)po0 * 512 + kp0 * 8;
            const u16* g1 = isrc + (size_t)po1 * 512 + kp1 * 8;
            for (int k0 = 0; k0 < 512; k0 += 32) {
                stage128x32(wsrc + k0, 512, As, t);
                gload_lds16((const void*)(g0 + k0), (void*)lb0);
                gload_lds16((const void*)(g1 + k0), (void*)lb1);
                __syncthreads();
                bf16x8 af[4], bfr[4];
#pragma unroll
                for (int i = 0; i < 4; i++) af[i] = *(const bf16x8*)&As[aoff[i]];
#pragma unroll
                for (int j = 0; j < 4; j++) bfr[j] = *(const bf16x8*)&Bs[boff[j]];
#pragma unroll
                for (int i = 0; i < 4; i++)
#pragma unroll
                    for (int j = 0; j < 4; j++)
                        acc[i][j] = __builtin_amdgcn_mfma_f32_16x16x32_bf16(af[i], bfr[j], acc[i][j], 0, 0, 0);
                __syncthreads();
            }
        }
    }
#pragma unroll
    for (int i = 0; i < 4; i++) {
        int ocbase = m0 + wm * 64 + i * 16 + kg * 4;
#pragma unroll
        for (int j = 0; j < 4; j++) {
            int c = wn * 64 + j * 16 + lm;
            int py = y0 + (c >> 6), px = c & 63;
#pragma unroll
            for (int r = 0; r < 4; r++) {
                int oc = ocbase + r;
                out[((size_t)(b * 512 + oc) << 12) + (py << 6) + px] = acc[i][j][r] + bias[oc];
            }
        }
    }
}

// ---------------- patchify (B,512,64,64) f32 -> (B,1024,2048) bf16 ----------------
__global__ void patchify_kernel(const float* __restrict__ hn, u16* __restrict__ pout) {
    int idx = blockIdx.x * 256 + threadIdx.x;
    int kf = idx & 2047;
    int tk = (idx >> 11) & 1023;
    int b = idx >> 21;
    int c = kf >> 2;
    int a = (kf >> 1) & 1;
    int b2 = kf & 1;
    int ph = tk >> 5, pw = tk & 31;
    pout[idx] = f2b(hn[(size_t)((b * 512 + c)) * 4096 + (((ph << 1) + a) << 6) + (pw << 1) + b2]);
}

// ---------------- layernorm + modulate (fp32 in, fp32 or bf16 out) ----------------
template <typename OT>
__global__ __launch_bounds__(256) void ln_mod_kernel(const float* __restrict__ in, OT* __restrict__ out,
                                                     const float* __restrict__ g, const float* __restrict__ bt,
                                                     const float* __restrict__ shiftb, const float* __restrict__ scaleb,
                                                     int modStride, float eps) {
    int row = blockIdx.x;
    int b = row >> 10;
    int t = threadIdx.x;
    const float* p = in + ((size_t)row << 10);
    float4 x = ((const float4*)p)[t];
    float s = x.x + x.y + x.z + x.w;
    float sq = x.x * x.x + x.y * x.y + x.z * x.z + x.w * x.w;
    __shared__ float2 red[256];
    red[t] = make_float2(s, sq);
    __syncthreads();
    for (int st = 128; st > 0; st >>= 1) {
        if (t < st) { red[t].x += red[t + st].x; red[t].y += red[t + st].y; }
        __syncthreads();
    }
    float mean = red[0].x * (1.f / 1024.f);
    float var = red[0].y * (1.f / 1024.f) - mean * mean;
    float rstd = rsqrtf(var + eps);
    const float* sh = shiftb + b * modStride;
    const float* sc = scaleb + b * modStride;
    int c = t << 2;
    float o0, o1, o2, o3;
    {
        float xn = (x.x - mean) * rstd; if (g) xn = xn * g[c + 0] + bt[c + 0];
        o0 = xn * (1.f + sc[c + 0]) + sh[c + 0];
    }
    {
        float xn = (x.y - mean) * rstd; if (g) xn = xn * g[c + 1] + bt[c + 1];
        o1 = xn * (1.f + sc[c + 1]) + sh[c + 1];
    }
    {
        float xn = (x.z - mean) * rstd; if (g) xn = xn * g[c + 2] + bt[c + 2];
        o2 = xn * (1.f + sc[c + 2]) + sh[c + 2];
    }
    {
        float xn = (x.w - mean) * rstd; if (g) xn = xn * g[c + 3] + bt[c + 3];
        o3 = xn * (1.f + sc[c + 3]) + sh[c + 3];
    }
    if constexpr (sizeof(OT) == 4) {
        float4 o = make_float4(o0, o1, o2, o3);
        ((float4*)(out + ((size_t)row << 10)))[t] = o;
    } else {
        ushort4 o;
        o.x = f2b(o0); o.y = f2b(o1); o.z = f2b(o2); o.w = f2b(o3);
        ((ushort4*)(out + ((size_t)row << 10)))[t] = o;
    }
}

// ---------------- rope cos/sin table: (1024 positions x 32 freqs) float2 ----------------
__global__ void rope_table_kernel(float* __restrict__ RT) {
    int idx = blockIdx.x * 256 + threadIdx.x;  // 32768
    int j = idx & 31;
    int tt = idx >> 5;
    float inv = powf(10000.f, -(float)j * (1.f / 32.f));
    float ang = (float)tt * inv;
    ((float2*)RT)[idx] = make_float2(cosf(ang), sinf(ang));
}

// ---------------- rope (in-place, bf16 (B,T,H,D)) using precomputed table ----------------
__global__ void rope_kernel(u16* __restrict__ p, const float* __restrict__ RT) {
    int idx = blockIdx.x * 256 + threadIdx.x;  // 2097152
    int j = idx & 31;
    int tt = (idx >> 9) & 1023;
    float2 cssn = ((const float2*)RT)[(tt << 5) + j];
    float cs = cssn.x, sn = cssn.y;
    int h = (idx >> 5) & 15;
    int b = idx >> 19;
    size_t base = (size_t)(((b << 10) + tt)) * 1024 + (h << 6) + (j << 1);
    ushort2 v = *(ushort2*)&p[base];
    float x = b2f(v.x), yv = b2f(v.y);
    ushort2 o;
    o.x = f2b(x * cs - yv * sn);
    o.y = f2b(x * sn + yv * cs);
    *(ushort2*)&p[base] = o;
}

// ---------------- V transpose bf16: (B,T,H,D) -> (B,H,D,T), LDS tiled ----------------
__global__ __launch_bounds__(256) void vtrans_kernel(const u16* __restrict__ v, u16* __restrict__ vT) {
    int st = blockIdx.x, h = blockIdx.y, b = blockIdx.z;
    int s0 = st << 6;
    __shared__ u16 tile[64][68];  // pad 4 -> 8B-aligned rows, spread banks
    int t = threadIdx.x;
#pragma unroll
    for (int rep = 0; rep < 4; rep++) {
        int i = rep * 256 + t;       // 0..1023
        int sl = i >> 4, d4 = (i & 15) << 2;
        *(ushort4*)&tile[sl][d4] =
            *(const ushort4*)&v[(size_t)((b << 10) + s0 + sl) * 1024 + (h << 6) + d4];
    }
    __syncthreads();
#pragma unroll
    for (int rep = 0; rep < 4; rep++) {
        int i = rep * 256 + t;
        int d = i >> 4, sl4 = (i & 15) << 2;
        ushort4 o;
        o.x = tile[sl4 + 0][d];
        o.y = tile[sl4 + 1][d];
        o.z = tile[sl4 + 2][d];
        o.w = tile[sl4 + 3][d];
        *(ushort4*)&vT[(size_t)(((b * 16 + h) << 6) + d) * 1024 + s0 + sl4] = o;
    }
}

// ---------------- fused flash attention via MFMA ----------------
// grid (8 q-tiles, 16 h, 4 b), 256 thr = 4 waves x 32 q-rows. K/V-tiles of 128.
// q,k: (B,T,H,D) bf16 (rope applied); vT: (B,H,D,T) bf16; o: (B,T,H,D) bf16
__global__ __launch_bounds__(256, 2) void attn_mfma_kernel(
    const u16* __restrict__ q, const u16* __restrict__ k,
    const u16* __restrict__ vT, u16* __restrict__ o) {
    __shared__ __align__(16) short Ks[128 * 64];    // 16 KB [s][d] swizzled
    __shared__ __align__(16) short Vts[64 * 128];   // 16 KB [d][s] swizzled
    __shared__ __align__(16) short Ps[4 * 32 * 128];// 32 KB per-wave [q][s] swizzled
    int t = threadIdx.x;
    int lane = t & 63, wm = t >> 6;
    int lm = lane & 15, kg = lane >> 4;
    int tq0 = blockIdx.x << 7, h = blockIdx.y, b = blockIdx.z;

    // Q fragments for this wave's 32 rows, held in regs for the whole kernel
    const u16* qbase = q + ((size_t)((b << 10) + tq0 + wm * 32)) * 1024 + (h << 6);
    bf16x8 afq[2][2];
#pragma unroll
    for (int i = 0; i < 2; i++)
#pragma unroll
        for (int kk = 0; kk < 2; kk++)
            afq[i][kk] = *(const bf16x8*)(qbase + (size_t)(i * 16 + lm) * 1024 + kk * 32 + kg * 8);

    floatx4 zero4 = {0.f, 0.f, 0.f, 0.f};
    floatx4 oacc[2][4];
    float m_[2][4], l_[2][4];
#pragma unroll
    for (int i = 0; i < 2; i++)
#pragma unroll
        for (int r = 0; r < 4; r++) { m_[i][r] = -3.0e38f; l_[i][r] = 0.f; }
#pragma unroll
    for (int i = 0; i < 2; i++)
#pragma unroll
        for (int jn = 0; jn < 4; jn++) oacc[i][jn] = zero4;

    const u16* kb0 = k + ((size_t)(b << 10)) * 1024 + (h << 6);
    const u16* vb0 = vT + ((size_t)((b * 16 + h) << 6)) * 1024;
    u16* Pw = (u16*)Ps + wm * 4096;

    for (int s0 = 0; s0 < 1024; s0 += 128) {
        stage_attn128x64(kb0 + (size_t)s0 * 1024, Ks, t);
        stage_attn64x128(vb0 + s0, Vts, t);
        __syncthreads();

        // ---- S = Q @ K^T ----
        floatx4 sacc[2][8];
#pragma unroll
        for (int i = 0; i < 2; i++)
#pragma unroll
            for (int j = 0; j < 8; j++) sacc[i][j] = zero4;
#pragma unroll
        for (int j = 0; j < 8; j++) {
            int row = j * 16 + lm;
            bf16x8 bk0 = *(const bf16x8*)&Ks[row * 64 + ((kg ^ (row & 7)) << 3)];
            bf16x8 bk1 = *(const bf16x8*)&Ks[row * 64 + (((4 + kg) ^ (row & 7)) << 3)];
#pragma unroll
            for (int i = 0; i < 2; i++) {
                sacc[i][j] = __builtin_amdgcn_mfma_f32_16x16x32_bf16(afq[i][0], bk0, sacc[i][j], 0, 0, 0);
                sacc[i][j] = __builtin_amdgcn_mfma_f32_16x16x32_bf16(afq[i][1], bk1, sacc[i][j], 0, 0, 0);
            }
        }

        // ---- online softmax (scale 0.125 folded into max/exp) ----
        float al[2][4], ps[2][4];
#pragma unroll
        for (int i = 0; i < 2; i++)
#pragma unroll
            for (int r = 0; r < 4; r++) {
                float v = sacc[i][0][r];
#pragma unroll
                for (int j = 1; j < 8; j++) v = fmaxf(v, sacc[i][j][r]);
                v = fmaxf(v, __shfl_xor(v, 1));
                v = fmaxf(v, __shfl_xor(v, 2));
                v = fmaxf(v, __shfl_xor(v, 4));
                v = fmaxf(v, __shfl_xor(v, 8));
                float mn = fmaxf(m_[i][r], v * 0.125f);
                al[i][r] = __expf(m_[i][r] - mn);
                m_[i][r] = mn;
                l_[i][r] *= al[i][r];
                ps[i][r] = 0.f;
            }
#pragma unroll
        for (int i = 0; i < 2; i++)
#pragma unroll
            for (int jn = 0; jn < 4; jn++)
#pragma unroll
                for (int r = 0; r < 4; r++) oacc[i][jn][r] *= al[i][r];

        // ---- P = exp(S*scale - m), write to per-wave swizzled LDS ----
#pragma unroll
        for (int i = 0; i < 2; i++)
#pragma unroll
            for (int j = 0; j < 8; j++) {
                int s = j * 16 + lm;
                int chunk = s >> 3;
#pragma unroll
                for (int r = 0; r < 4; r++) {
                    int qr = i * 16 + kg * 4 + r;
                    float e = __expf(fmaf(sacc[i][j][r], 0.125f, -m_[i][r]));
                    ps[i][r] += e;
                    int cs = (chunk & 8) | ((chunk ^ qr) & 7);
                    Pw[qr * 128 + cs * 8 + (s & 7)] = f2b(e);
                }
            }
#pragma unroll
        for (int i = 0; i < 2; i++)
#pragma unroll
            for (int r = 0; r < 4; r++) {
                float v = ps[i][r];
                v += __shfl_xor(v, 1);
                v += __shfl_xor(v, 2);
                v += __shfl_xor(v, 4);
                v += __shfl_xor(v, 8);
                l_[i][r] += v;
            }

        // ---- O += P @ V  (A = P [q][s], B = V^T [d][s]) ----
#pragma unroll
        for (int ks = 0; ks < 4; ks++) {
            int chunk = ks * 4 + kg;
            bf16x8 pa[2];
#pragma unroll
            for (int i = 0; i < 2; i++) {
                int qr = i * 16 + lm;
                int cs = (chunk & 8) | ((chunk ^ qr) & 7);
                pa[i] = *(const bf16x8*)&Pw[qr * 128 + cs * 8];
            }
#pragma unroll
            for (int jn = 0; jn < 4; jn++) {
                int row = jn * 16 + lm;
                int cs = (chunk & 8) | ((chunk ^ row) & 7);
                bf16x8 bv = *(const bf16x8*)&Vts[row * 128 + cs * 8];
#pragma unroll
                for (int i = 0; i < 2; i++)
                    oacc[i][jn] = __builtin_amdgcn_mfma_f32_16x16x32_bf16(pa[i], bv, oacc[i][jn], 0, 0, 0);
            }
        }
        __syncthreads();
    }

    // ---- epilogue: O /= l ----
    u16* obase = o + ((size_t)((b << 10) + tq0 + wm * 32)) * 1024 + (h << 6);
#pragma unroll
    for (int i = 0; i < 2; i++)
#pragma unroll
        for (int r = 0; r < 4; r++) {
            float inv = 1.f / l_[i][r];
            int qr = i * 16 + kg * 4 + r;
#pragma unroll
            for (int jn = 0; jn < 4; jn++)
                obase[(size_t)qr * 1024 + jn * 16 + lm] = f2b(oacc[i][jn][r] * inv);
        }
}

// ---------------- small row-vector GEMM (fp32) ----------------
__global__ __launch_bounds__(256) void rowvec_gemm_kernel(const float* __restrict__ A, const float* __restrict__ W,
                                                          const float* __restrict__ bias, float* __restrict__ out,
                                                          int N, int K) {
    int wid = blockIdx.x * 4 + (threadIdx.x >> 6);
    int lane = threadIdx.x & 63;
    int b = wid / N, n = wid - b * N;
    const float* a = A + (size_t)b * K;
    const float* w = W + (size_t)n * K;
    float s = 0.f;
    for (int k = lane << 2; k < K; k += 256) {
        float4 av = *(const float4*)&a[k];
        float4 wv = *(const float4*)&w[k];
        s += av.x * wv.x + av.y * wv.y + av.z * wv.z + av.w * wv.w;
    }
#pragma unroll
    for (int off = 32; off > 0; off >>= 1) s += __shfl_xor(s, off);
    if (lane == 0) out[wid] = s + (bias ? bias[n] : 0.f);
}

// ---------------- final projection: (4096x1024) @ (16x1024)^T + bias (fp32) ----------------
__global__ __launch_bounds__(256) void fin_gemm_kernel(const float* __restrict__ zf, const float* __restrict__ w,
                                                       const float* __restrict__ bias, float* __restrict__ out) {
    int idx = blockIdx.x * 256 + threadIdx.x;  // 65536
    int m = idx >> 4, n = idx & 15;
    const float* a = zf + ((size_t)m << 10);
    const float* wp = w + ((size_t)n << 10);
    float s = 0.f;
    for (int k = 0; k < 1024; k += 4) {
        float4 av = *(const float4*)&a[k];
        float4 wv = *(const float4*)&wp[k];
        s += av.x * wv.x + av.y * wv.y + av.z * wv.z + av.w * wv.w;
    }
    out[idx] = s + bias[n];
}

// ---------------- unpatchify -> (B,4,64,64) ----------------
__global__ void unpatch_kernel(const float* __restrict__ ot, float* __restrict__ out) {
    int idx = blockIdx.x * 256 + threadIdx.x;  // 65536
    int x = idx & 63;
    int yy = (idx >> 6) & 63;
    int ci = (idx >> 12) & 3;
    int b = idx >> 14;
    out[idx] = ot[(size_t)(((b << 10) + ((yy >> 1) << 5) + (x >> 1))) * 16 + (((yy & 1) << 1) + (x & 1)) * 4 + ci];
}

// ---------------- host orchestration ----------------
extern "C" void kernel_launch(void* const* d_in, const int* in_sizes, int n_in,
                              void* d_out, int out_size, void* d_ws, size_t ws_size,
                              hipStream_t stream) {
    const float* x       = (const float*)d_in[0];
    const float* tin     = (const float*)d_in[1];
    const int*   y       = (const int*)d_in[2];
    const float* conv1_w = (const float*)d_in[3];
    const float* conv1_b = (const float*)d_in[4];
    const float* gn1_g   = (const float*)d_in[5];
    const float* gn1_b   = (const float*)d_in[6];
    const float* conv2_w = (const float*)d_in[7];
    const float* conv2_b = (const float*)d_in[8];
    const float* gn2_g   = (const float*)d_in[9];
    const float* gn2_b   = (const float*)d_in[10];
    const float* xemb_w  = (const float*)d_in[11];
    const float* xemb_b  = (const float*)d_in[12];
    const float* t1_w    = (const float*)d_in[13];
    const float* t1_b    = (const float*)d_in[14];
    const float* t2_w    = (const float*)d_in[15];
    const float* t2_b    = (const float*)d_in[16];
    const float* y_emb   = (const float*)d_in[17];
    const float* wq      = (const float*)d_in[18];
    const float* wk      = (const float*)d_in[19];
    const float* wv      = (const float*)d_in[20];
    const float* wo      = (const float*)d_in[21];
    const float* w1      = (const float*)d_in[22];
    const float* w3      = (const float*)d_in[23];   // dict order: w1, w3, w2
    const float* w2      = (const float*)d_in[24];
    const float* ada_w   = (const float*)d_in[25];
    const float* ada_b   = (const float*)d_in[26];
    const float* an_g    = (const float*)d_in[27];
    const float* an_b    = (const float*)d_in[28];
    const float* fn_g    = (const float*)d_in[29];
    const float* fn_b    = (const float*)d_in[30];
    const float* fin_ada_w = (const float*)d_in[31];
    const float* fin_ada_b = (const float*)d_in[32];
    const float* fin_w   = (const float*)d_in[33];
    const float* fin_b   = (const float*)d_in[34];

    char* wsb = (char*)d_ws;
    // byte layout (total ~112.5 MB)
    float* Z    = (float*)(wsb + 0);               // 16 MB residual stream (fp32)
    u16*  Wbf   = (u16*)(wsb + (16ull << 20));     // 18 MB per-layer bf16 weights
    u16*  HHb   = (u16*)(wsb + (34ull << 20));     // 8 MB ln/mod output bf16
    u16*  Qb    = (u16*)(wsb + (42ull << 20));     // 8 MB
    u16*  Kb    = (u16*)(wsb + (50ull << 20));     // 8 MB
    u16*  Vb    = (u16*)(wsb + (58ull << 20));     // 8 MB
    u16*  VTb   = (u16*)(wsb + (66ull << 20));     // 8 MB V transposed (B,H,D,T)
    u16*  AOb   = (u16*)(wsb + (74ull << 20));     // 8 MB attn out bf16
    u16*  F1b   = (u16*)(wsb + (82ull << 20));     // 23.1 MB ff hidden bf16
    // stem-phase overlays (dead once the transformer starts)
    float* A0f  = (float*)(wsb + (42ull << 20));   // 33.6 MB
    float* A1f  = (float*)(wsb + (76ull << 20));   // 33.6 MB (ends ~109.6 MB)
    u16*  IPad  = (u16*)(wsb + 0);                 // 18.1 MB padded NHWC bf16 (overlays Z; dead before Z written)
    u16*  WTc   = (u16*)(wsb + (20ull << 20));     // 12.5 MB conv2 tap-major bf16 weights
    u16*  PATb  = (u16*)(wsb + (16ull << 20));     // 16.8 MB patches bf16
    u16*  XWb   = (u16*)(wsb + (34ull << 20));     // 4 MB xemb_w bf16
    float* ZF   = (float*)(wsb + (42ull << 20));   // final zf fp32 (over Qb/Kb)
    float* SM   = (float*)(wsb + (110ull << 20));  // small buffers
    float* TMB  = SM;            // 4096
    float* CSI  = TMB + 4096;    // 4096
    float* MODS = CSI + 4096;    // 24576
    float* FM   = MODS + 24576;  // 8192
    float* OT   = FM + 8192;     // 65536
    float* RT   = (float*)(wsb + (112ull << 20));  // 256 KB rope table

    // constant prep (no activation deps)
    hipMemsetAsync(IPad, 0, (size_t)4 * 68 * 68 * 512 * 2, stream);
    rope_table_kernel<<<128, 256, 0, stream>>>(RT);
    wtrans25_kernel<<<1024, 256, 0, stream>>>(conv2_w, WTc);

    // conditioning
    temb1_kernel<<<16, 256, 0, stream>>>(tin, t1_w, t1_b, TMB);
    temb2_kernel<<<1024, 256, 0, stream>>>(TMB, t2_w, t2_b, y_emb, y, CSI);

    // conv stem
    conv1_kernel<<<32768, 256, 0, stream>>>(x, conv1_w, conv1_b, A0f);
    silu_gn_kernel<<<128, 256, 0, stream>>>(A0f, A1f, gn1_g, gn1_b);
    nchw2nhwc_pad_kernel<<<4096, 256, 0, stream>>>(A1f, IPad);
    conv2_mfma_kernel<<<dim3(128, 4), 256, 0, stream>>>(IPad, WTc, conv2_b, A0f);
    silu_gn_kernel<<<128, 256, 0, stream>>>(A0f, A1f, gn2_g, gn2_b);
    patchify_kernel<<<32768, 256, 0, stream>>>(A1f, PATb);
    f2bN_kernel<<<2048, 256, 0, stream>>>(xemb_w, nullptr, nullptr, nullptr, XWb, 524288, 1);
    mfma_gemm_kernel<<<dim3(8, 32), 256, 0, stream>>>(PATb, XWb, 4096, 1024, 2048,
                                                      Z, nullptr, xemb_b, nullptr, nullptr, 0);

    for (int i = 0; i < NLAYERS; i++) {
        const float* wq_i = wq + (size_t)i * 1048576;
        const float* wk_i = wk + (size_t)i * 1048576;
        const float* wv_i = wv + (size_t)i * 1048576;
        const float* wo_i = wo + (size_t)i * 1048576;
        const float* w1_i = w1 + (size_t)i * 2883584;
        const float* w3_i = w3 + (size_t)i * 2883584;
        const float* w2_i = w2 + (size_t)i * 2883584;
        const float* ada_w_i = ada_w + (size_t)i * 6291456;
        const float* ada_b_i = ada_b + (size_t)i * 6144;

        // bf16 weights for attn part: [wq|wk|wv|wo]
        f2bN_kernel<<<4096, 256, 0, stream>>>(wq_i, wk_i, wv_i, wo_i, Wbf, 262144, 4);
        // adaLN mods (fp32)
        rowvec_gemm_kernel<<<6144, 256, 0, stream>>>(CSI, ada_w_i, ada_b_i, MODS, 6144, 1024);
        // attn branch
        ln_mod_kernel<u16><<<4096, 256, 0, stream>>>(Z, HHb, an_g + i * 1024, an_b + i * 1024,
                                                     MODS + 0, MODS + 1024, 6144, 1e-5f);
        mfma_gemm_kernel<<<dim3(8, 32), 256, 0, stream>>>(HHb, Wbf + 0ull, 4096, 1024, 1024,
                                                          nullptr, Qb, nullptr, nullptr, nullptr, 0);
        mfma_gemm_kernel<<<dim3(8, 32), 256, 0, stream>>>(HHb, Wbf + 1048576ull, 4096, 1024, 1024,
                                                          nullptr, Kb, nullptr, nullptr, nullptr, 0);
        mfma_gemm_kernel<<<dim3(8, 32), 256, 0, stream>>>(HHb, Wbf + 2097152ull, 4096, 1024, 1024,
                                                          nullptr, Vb, nullptr, nullptr, nullptr, 0);
        rope_kernel<<<8192, 256, 0, stream>>>(Qb, RT);
        rope_kernel<<<8192, 256, 0, stream>>>(Kb, RT);
        vtrans_kernel<<<dim3(16, 16, 4), 256, 0, stream>>>(Vb, VTb);
        attn_mfma_kernel<<<dim3(8, 16, 4), 256, 0, stream>>>(Qb, Kb, VTb, AOb);
        mfma_gemm_kernel<<<dim3(8, 32), 256, 0, stream>>>(AOb, Wbf + 3145728ull, 4096, 1024, 1024,
                                                          nullptr, nullptr, nullptr, Z, MODS + 2048, 6144);
        // ff branch
        ln_mod_kernel<u16><<<4096, 256, 0, stream>>>(Z, HHb, fn_g + i * 1024, fn_b + i * 1024,
                                                     MODS + 3072, MODS + 4096, 6144, 1e-5f);
        f2bN_kernel<<<8448, 256, 0, stream>>>(w1_i, w3_i, w2_i, nullptr, Wbf, 720896, 3);
        mfma_gemm_swiglu_kernel<<<dim3(22, 32), 256, 0, stream>>>(HHb, Wbf, Wbf + 2883584ull,
                                                                  4096, 2816, 1024, F1b);
        mfma_gemm_kernel<<<dim3(8, 32), 256, 0, stream>>>(F1b, Wbf + 5767168ull, 4096, 1024, 2816,
                                                          nullptr, nullptr, nullptr, Z, MODS + 5120, 6144);
    }

    // final head
    rowvec_gemm_kernel<<<2048, 256, 0, stream>>>(CSI, fin_ada_w, fin_ada_b, FM, 2048, 1024);
    ln_mod_kernel<float><<<4096, 256, 0, stream>>>(Z, ZF, nullptr, nullptr, FM + 0, FM + 1024, 2048, 1e-6f);
    fin_gemm_kernel<<<256, 256, 0, stream>>>(ZF, fin_w, fin_b, OT);
    unpatch_kernel<<<256, 256, 0, stream>>>(OT, (float*)d_out);
}

// Round 3
// 3462.799 us; speedup vs baseline: 2.8793x; 1.1209x over previous
//
#include <hip/hip_runtime.h>
#include <math.h>

#define NLAYERS 6

typedef unsigned short u16;
typedef unsigned int u32;
typedef __attribute__((ext_vector_type(4))) float floatx4;
typedef __attribute__((ext_vector_type(8))) short bf16x8;

__device__ __forceinline__ float silu_f(float x) { return x / (1.0f + __expf(-x)); }

__device__ __forceinline__ u16 f2b(float f) {
    union { float f; u32 u; } x; x.f = f;
    u32 r = x.u + 0x7fffu + ((x.u >> 16) & 1u);
    return (u16)(r >> 16);
}
__device__ __forceinline__ float b2f(u16 u) {
    union { u32 u; float f; } x; x.u = ((u32)u) << 16;
    return x.f;
}

__device__ __forceinline__ void gload_lds16(const void* g, void* l) {
    __builtin_amdgcn_global_load_lds((const __attribute__((address_space(1))) u32*)g,
                                     (__attribute__((address_space(3))) u32*)l, 16, 0, 0);
}

// stage a 128-row x 32-col bf16 tile (row-major [128][32]) from global (row stride ldk) into LDS
__device__ __forceinline__ void stage128x32(const u16* __restrict__ src, int ldk, short* lds, int t) {
    int w = t >> 6;
#pragma unroll
    for (int rep = 0; rep < 2; rep++) {
        int s = rep * 256 + t;
        int row = s >> 2, kp = s & 3;
        const u16* g = src + (size_t)row * ldk + kp * 8;
        short* lb = lds + (size_t)(rep * 256 + w * 64) * 8;  // wave-uniform base
        gload_lds16((const void*)g, (void*)lb);
    }
}

// stage a 64-row x 32-col bf16 tile (row-major [64][32])
__device__ __forceinline__ void stage64x32(const u16* __restrict__ src, int ldk, short* lds, int t) {
    int w = t >> 6;
    int row = t >> 2, kp = t & 3;
    const u16* g = src + (size_t)row * ldk + kp * 8;
    short* lb = lds + (size_t)(w * 64) * 8;  // wave-uniform base
    gload_lds16((const void*)g, (void*)lb);
}

// stage 128 rows x 64 cols bf16 from (row stride 1024) global into LDS [128][64],
// with source-chunk XOR swizzle: LDS[row][cc] = global[row][cc ^ (row&7)]
__device__ __forceinline__ void stage_attn128x64(const u16* __restrict__ base, short* lds, int t) {
    int w = t >> 6;
#pragma unroll
    for (int rep = 0; rep < 4; rep++) {
        int cid = rep * 256 + t;
        int row = cid >> 3, cc = cid & 7;
        int gcc = cc ^ (row & 7);
        const u16* g = base + (size_t)row * 1024 + gcc * 8;
        short* lb = lds + (size_t)(rep * 256 + w * 64) * 8;
        gload_lds16((const void*)g, (void*)lb);
    }
}

// stage 64 rows x 128 cols bf16 from (row stride 1024) global into LDS [64][128],
// swizzle on low 3 chunk bits: LDS[row][cc] = global[row][(cc&8)|((cc^row)&7)]
__device__ __forceinline__ void stage_attn64x128(const u16* __restrict__ base, short* lds, int t) {
    int w = t >> 6;
#pragma unroll
    for (int rep = 0; rep < 4; rep++) {
        int cid = rep * 256 + t;
        int row = cid >> 4, cc = cid & 15;
        int gcc = (cc & 8) | ((cc ^ row) & 7);
        const u16* g = base + (size_t)row * 1024 + gcc * 8;
        short* lb = lds + (size_t)(rep * 256 + w * 64) * 8;
        gload_lds16((const void*)g, (void*)lb);
    }
}

// ---------------- fused QKV GEMM + RoPE epilogue ----------------
// A (4096 x 1024) bf16, W (3072 x 1024) bf16 = [wq|wk|wv] rows.
// Q,K get rope via cos/sin table; outputs bf16 (B,T,H*D) token-major.
__global__ __launch_bounds__(256) void mfma_qkv_kernel(
    const u16* __restrict__ A, const u16* __restrict__ W, const float* __restrict__ RT,
    u16* __restrict__ Qb, u16* __restrict__ Kb, u16* __restrict__ Vb) {
    const int K = 1024;
    __shared__ __align__(16) short As[128 * 32];
    __shared__ __align__(16) short Bs[128 * 32];
    int t = threadIdx.x;
    int lane = t & 63, wave = t >> 6;
    int wm = wave >> 1, wn = wave & 1;
    int m0 = blockIdx.y << 7, n0 = blockIdx.x << 7;
    int lm = lane & 15, kg = lane >> 4;
    floatx4 zero4 = {0.f, 0.f, 0.f, 0.f};
    floatx4 acc[4][4];
#pragma unroll
    for (int i = 0; i < 4; i++)
#pragma unroll
        for (int j = 0; j < 4; j++) acc[i][j] = zero4;
    const u16* Arow = A + (size_t)m0 * K;
    const u16* Wrow = W + (size_t)n0 * K;
    int aoff[4], boff[4];
#pragma unroll
    for (int i = 0; i < 4; i++) {
        aoff[i] = (wm * 64 + i * 16 + lm) * 32 + kg * 8;
        boff[i] = (wn * 64 + i * 16 + lm) * 32 + kg * 8;
    }
    for (int k0 = 0; k0 < K; k0 += 32) {
        stage128x32(Arow + k0, K, As, t);
        stage128x32(Wrow + k0, K, Bs, t);
        __syncthreads();
        bf16x8 af[4], bfr[4];
#pragma unroll
        for (int i = 0; i < 4; i++) af[i] = *(const bf16x8*)&As[aoff[i]];
#pragma unroll
        for (int j = 0; j < 4; j++) bfr[j] = *(const bf16x8*)&Bs[boff[j]];
#pragma unroll
        for (int i = 0; i < 4; i++)
#pragma unroll
            for (int j = 0; j < 4; j++)
                acc[i][j] = __builtin_amdgcn_mfma_f32_16x16x32_bf16(af[i], bfr[j], acc[i][j], 0, 0, 0);
        __syncthreads();
    }
#pragma unroll
    for (int i = 0; i < 4; i++) {
        int rbase = m0 + wm * 64 + i * 16 + kg * 4;
#pragma unroll
        for (int j = 0; j < 4; j++) {
            int c = n0 + wn * 64 + j * 16 + lm;
            int which = c >> 10, cc = c & 1023;           // wave-uniform 'which'
            u16* outp = (which == 0) ? Qb : (which == 1) ? Kb : Vb;
            int fi = (cc >> 1) & 31;
#pragma unroll
            for (int r = 0; r < 4; r++) {
                int row = rbase + r;
                float v = acc[i][j][r];
                float pv = __shfl_xor(v, 1);              // rope partner (all lanes)
                float res = v;
                if (which < 2) {
                    int tt = row & 1023;
                    float2 cssn = ((const float2*)RT)[(tt << 5) + fi];
                    res = (lane & 1) ? fmaf(pv, cssn.y, v * cssn.x)
                                     : fmaf(v, cssn.x, -pv * cssn.y);
                }
                outp[(size_t)row * 1024 + cc] = f2b(res);
            }
        }
    }
}

// ---------------- BN=64 MFMA GEMM (2 blocks/CU for N=1024 shapes) ----------------
// C(Mx N) = A(MxK) @ W(NxK)^T ; accZ mode: Z += gate*acc ; else outF = acc (+bias)
__global__ __launch_bounds__(256) void mfma_gemm64_kernel(
    const u16* __restrict__ A, const u16* __restrict__ W, int M, int N, int K,
    float* __restrict__ outF, const float* __restrict__ bias,
    float* __restrict__ accZ, const float* __restrict__ gate, int gateStride) {
    __shared__ __align__(16) short As[128 * 32];
    __shared__ __align__(16) short Bs[64 * 32];
    int t = threadIdx.x;
    int lane = t & 63, wave = t >> 6;
    int wm = wave >> 1, wn = wave & 1;    // wave tile 64 x 32
    int m0 = blockIdx.y << 7, n0 = blockIdx.x << 6;
    int lm = lane & 15, kg = lane >> 4;
    floatx4 zero4 = {0.f, 0.f, 0.f, 0.f};
    floatx4 acc[4][2];
#pragma unroll
    for (int i = 0; i < 4; i++)
#pragma unroll
        for (int j = 0; j < 2; j++) acc[i][j] = zero4;
    const u16* Arow = A + (size_t)m0 * K;
    const u16* Wrow = W + (size_t)n0 * K;
    int aoff[4], boff[2];
#pragma unroll
    for (int i = 0; i < 4; i++) aoff[i] = (wm * 64 + i * 16 + lm) * 32 + kg * 8;
#pragma unroll
    for (int j = 0; j < 2; j++) boff[j] = (wn * 32 + j * 16 + lm) * 32 + kg * 8;
    for (int k0 = 0; k0 < K; k0 += 32) {
        stage128x32(Arow + k0, K, As, t);
        stage64x32(Wrow + k0, K, Bs, t);
        __syncthreads();
        bf16x8 af[4], bfr[2];
#pragma unroll
        for (int i = 0; i < 4; i++) af[i] = *(const bf16x8*)&As[aoff[i]];
#pragma unroll
        for (int j = 0; j < 2; j++) bfr[j] = *(const bf16x8*)&Bs[boff[j]];
#pragma unroll
        for (int i = 0; i < 4; i++)
#pragma unroll
            for (int j = 0; j < 2; j++)
                acc[i][j] = __builtin_amdgcn_mfma_f32_16x16x32_bf16(af[i], bfr[j], acc[i][j], 0, 0, 0);
        __syncthreads();
    }
#pragma unroll
    for (int i = 0; i < 4; i++) {
        int rbase = m0 + wm * 64 + i * 16 + kg * 4;
#pragma unroll
        for (int j = 0; j < 2; j++) {
            int c = n0 + wn * 32 + j * 16 + lm;
#pragma unroll
            for (int r = 0; r < 4; r++) {
                float v = acc[i][j][r];
                int row = rbase + r;
                size_t off = (size_t)row * N + c;
                if (accZ) {
                    accZ[off] += gate[(row >> 10) * gateStride + c] * v;
                } else {
                    if (bias) v += bias[c];
                    outF[off] = v;
                }
            }
        }
    }
}

// ---------------- fused w1/w3 + swiglu: out = bf16( silu(A@W1^T) * (A@W3^T) ) ----------------
__global__ __launch_bounds__(256) void mfma_gemm_swiglu_kernel(
    const u16* __restrict__ A, const u16* __restrict__ W1, const u16* __restrict__ W3,
    int M, int N, int K, u16* __restrict__ outB) {
    __shared__ __align__(16) short As[128 * 32];
    __shared__ __align__(16) short B1s[128 * 32];
    __shared__ __align__(16) short B3s[128 * 32];
    int t = threadIdx.x;
    int lane = t & 63, wave = t >> 6;
    int wm = wave >> 1, wn = wave & 1;
    int m0 = blockIdx.y << 7, n0 = blockIdx.x << 7;
    int lm = lane & 15, kg = lane >> 4;
    floatx4 zero4 = {0.f, 0.f, 0.f, 0.f};
    floatx4 acc1[4][4], acc3[4][4];
#pragma unroll
    for (int i = 0; i < 4; i++)
#pragma unroll
        for (int j = 0; j < 4; j++) { acc1[i][j] = zero4; acc3[i][j] = zero4; }
    const u16* Arow = A + (size_t)m0 * K;
    const u16* W1row = W1 + (size_t)n0 * K;
    const u16* W3row = W3 + (size_t)n0 * K;
    int aoff[4], boff[4];
#pragma unroll
    for (int i = 0; i < 4; i++) {
        aoff[i] = (wm * 64 + i * 16 + lm) * 32 + kg * 8;
        boff[i] = (wn * 64 + i * 16 + lm) * 32 + kg * 8;
    }
    for (int k0 = 0; k0 < K; k0 += 32) {
        stage128x32(Arow + k0, K, As, t);
        stage128x32(W1row + k0, K, B1s, t);
        stage128x32(W3row + k0, K, B3s, t);
        __syncthreads();
        bf16x8 af[4], b1[4], b3[4];
#pragma unroll
        for (int i = 0; i < 4; i++) af[i] = *(const bf16x8*)&As[aoff[i]];
#pragma unroll
        for (int j = 0; j < 4; j++) { b1[j] = *(const bf16x8*)&B1s[boff[j]]; b3[j] = *(const bf16x8*)&B3s[boff[j]]; }
#pragma unroll
        for (int i = 0; i < 4; i++)
#pragma unroll
            for (int j = 0; j < 4; j++) {
                acc1[i][j] = __builtin_amdgcn_mfma_f32_16x16x32_bf16(af[i], b1[j], acc1[i][j], 0, 0, 0);
                acc3[i][j] = __builtin_amdgcn_mfma_f32_16x16x32_bf16(af[i], b3[j], acc3[i][j], 0, 0, 0);
            }
        __syncthreads();
    }
#pragma unroll
    for (int i = 0; i < 4; i++) {
        int rbase = m0 + wm * 64 + i * 16 + kg * 4;
#pragma unroll
        for (int j = 0; j < 4; j++) {
            int c = n0 + wn * 64 + j * 16 + lm;
#pragma unroll
            for (int r = 0; r < 4; r++) {
                int row = rbase + r;
                float v = silu_f(acc1[i][j][r]) * acc3[i][j][r];
                outB[(size_t)row * N + c] = f2b(v);
            }
        }
    }
}

// ---------------- fp32 -> bf16 conversion (up to 4 equal-size arrays) ----------------
__global__ void f2bN_kernel(const float* __restrict__ p0, const float* __restrict__ p1,
                            const float* __restrict__ p2, const float* __restrict__ p3,
                            u16* __restrict__ out, int n4each, int nptr) {
    int idx = blockIdx.x * 256 + threadIdx.x;
    if (idx >= n4each * nptr) return;
    int which = idx / n4each;
    int i = idx - which * n4each;
    const float* p = (which == 0) ? p0 : (which == 1) ? p1 : (which == 2) ? p2 : p3;
    float4 v = ((const float4*)p)[i];
    ushort4 o;
    o.x = f2b(v.x); o.y = f2b(v.y); o.z = f2b(v.z); o.w = f2b(v.w);
    ((ushort4*)out)[idx] = o;
}

// ---------------- temb ----------------
__global__ void temb1_kernel(const float* __restrict__ t, const float* __restrict__ w,
                             const float* __restrict__ b, float* __restrict__ out) {
    int idx = blockIdx.x * 256 + threadIdx.x;
    int bb = idx >> 10, n = idx & 1023;
    out[idx] = silu_f(t[bb] * w[n] + b[n]);
}

__global__ __launch_bounds__(256) void temb2_kernel(const float* __restrict__ A, const float* __restrict__ W,
                                                    const float* __restrict__ b2, const float* __restrict__ yemb,
                                                    const int* __restrict__ y, float* __restrict__ out) {
    int wid = blockIdx.x * 4 + (threadIdx.x >> 6);
    int lane = threadIdx.x & 63;
    int bb = wid >> 10, n = wid & 1023;
    const float* a = A + (bb << 10);
    const float* w = W + (n << 10);
    float s = 0.f;
    for (int k = lane << 2; k < 1024; k += 256) {
        float4 av = *(const float4*)&a[k];
        float4 wv = *(const float4*)&w[k];
        s += av.x * wv.x + av.y * wv.y + av.z * wv.z + av.w * wv.w;
    }
#pragma unroll
    for (int off = 32; off > 0; off >>= 1) s += __shfl_xor(s, off);
    if (lane == 0) {
        float vv = s + b2[n] + yemb[(size_t)y[bb] * 1024 + n];
        out[wid] = silu_f(vv);
    }
}

// ---------------- conv1: 4 -> 512, 5x5 SAME ----------------
__global__ __launch_bounds__(256) void conv1_kernel(const float* __restrict__ x, const float* __restrict__ w,
                                                    const float* __restrict__ bias, float* __restrict__ out) {
    int idx = blockIdx.x * 256 + threadIdx.x;
    int px = idx & 63;
    int py = (idx >> 6) & 63;
    int oc = (idx >> 12) & 511;
    int b = idx >> 21;
    float acc = bias[oc];
    for (int ic = 0; ic < 4; ic++) {
        const float* xp = x + (((b << 2) + ic) << 12);
        const float* wp = w + (oc * 4 + ic) * 25;
#pragma unroll
        for (int ky = 0; ky < 5; ky++) {
            int iy = py + ky - 2;
            if (iy < 0 || iy > 63) continue;
#pragma unroll
            for (int kx = 0; kx < 5; kx++) {
                int ix = px + kx - 2;
                if (ix < 0 || ix > 63) continue;
                acc += xp[(iy << 6) + ix] * wp[ky * 5 + kx];
            }
        }
    }
    out[idx] = acc;
}

// ---------------- fused silu + groupnorm ----------------
__global__ __launch_bounds__(256) void silu_gn_kernel(const float* __restrict__ in, float* __restrict__ out,
                                                      const float* __restrict__ g, const float* __restrict__ bt) {
    int blk = blockIdx.x;
    int b = blk >> 5, grp = blk & 31, c0 = grp << 4;
    const float* p = in + (size_t)((b * 512 + c0)) * 4096;
    float* q = out + (size_t)((b * 512 + c0)) * 4096;
    int t = threadIdx.x;
    float s = 0.f, sq = 0.f;
    for (int i = t; i < 16384; i += 256) {
        float4 v = ((const float4*)p)[i];
        float a0 = silu_f(v.x), a1 = silu_f(v.y), a2 = silu_f(v.z), a3 = silu_f(v.w);
        s += a0 + a1 + a2 + a3;
        sq += a0 * a0 + a1 * a1 + a2 * a2 + a3 * a3;
    }
    __shared__ float2 red[256];
    red[t] = make_float2(s, sq);
    __syncthreads();
    for (int st = 128; st > 0; st >>= 1) {
        if (t < st) { red[t].x += red[t + st].x; red[t].y += red[t + st].y; }
        __syncthreads();
    }
    float mean = red[0].x * (1.f / 65536.f);
    float var = red[0].y * (1.f / 65536.f) - mean * mean;
    float rstd = rsqrtf(var + 1e-5f);
    for (int i = t; i < 16384; i += 256) {
        float4 v = ((const float4*)p)[i];
        int ch = c0 + (i >> 10);
        float gg = g[ch], bb = bt[ch];
        float4 o;
        o.x = (silu_f(v.x) - mean) * rstd * gg + bb;
        o.y = (silu_f(v.y) - mean) * rstd * gg + bb;
        o.z = (silu_f(v.z) - mean) * rstd * gg + bb;
        o.w = (silu_f(v.w) - mean) * rstd * gg + bb;
        ((float4*)q)[i] = o;
    }
}

// ---------------- NCHW fp32 -> padded NHWC bf16 (B,68,68,512), interior only ----------------
__global__ __launch_bounds__(256) void nchw2nhwc_pad_kernel(const float* __restrict__ in, u16* __restrict__ out) {
    int blk = blockIdx.x;  // 4096 = b(4) * y(64) * ct(16)
    int ct = blk & 15;
    int yy = (blk >> 4) & 63;
    int b = blk >> 10;
    __shared__ float tile[32][65];
    int t = threadIdx.x;
    const float* ip = in + (((size_t)(b * 512 + (ct << 5))) << 12) + (yy << 6);
    for (int i = t; i < 2048; i += 256) {
        int cl = i >> 6, x = i & 63;
        tile[cl][x] = ip[((size_t)cl << 12) + x];
    }
    __syncthreads();
    u16* op = out + ((size_t)((b * 68 + yy + 2) * 68 + 2)) * 512 + (ct << 5);
    for (int i = t; i < 2048; i += 256) {
        int x = i >> 5, cl = i & 31;
        op[(size_t)x * 512 + cl] = f2b(tile[cl][x]);
    }
}

// ---------------- conv2_w (oc,ic,5,5) fp32 -> 25 tap-major (oc,ic) bf16 matrices ----------------
__global__ __launch_bounds__(256) void wtrans25_kernel(const float* __restrict__ w, u16* __restrict__ wt) {
    int idx = blockIdx.x * 256 + threadIdx.x;  // 262144 = oc*512 + ic
    const float* p = w + (size_t)idx * 25;
#pragma unroll
    for (int tap = 0; tap < 25; tap++)
        wt[(size_t)tap * 262144 + idx] = f2b(p[tap]);
}

// ---------------- conv2 as implicit GEMM via MFMA ----------------
__global__ __launch_bounds__(256) void conv2_mfma_kernel(
    const u16* __restrict__ Ipad, const u16* __restrict__ Wt,
    const float* __restrict__ bias, float* __restrict__ out) {
    __shared__ __align__(16) short As[128 * 32];
    __shared__ __align__(16) short Bs[128 * 32];
    int t = threadIdx.x;
    int lane = t & 63, wave = t >> 6;
    int wm = wave >> 1, wn = wave & 1;
    int m0 = blockIdx.y << 7;          // oc tile base (0..511 step 128)
    int b = blockIdx.x >> 5;           // batch
    int y0 = (blockIdx.x & 31) << 1;   // output row pair
    int lm = lane & 15, kg = lane >> 4;
    floatx4 zero4 = {0.f, 0.f, 0.f, 0.f};
    floatx4 acc[4][4];
#pragma unroll
    for (int i = 0; i < 4; i++)
#pragma unroll
        for (int j = 0; j < 4; j++) acc[i][j] = zero4;
    int aoff[4], boff[4];
#pragma unroll
    for (int i = 0; i < 4; i++) {
        aoff[i] = (wm * 64 + i * 16 + lm) * 32 + kg * 8;
        boff[i] = (wn * 64 + i * 16 + lm) * 32 + kg * 8;
    }
    int s0 = t, s1 = 256 + t;
    int row0 = s0 >> 2, kp0 = s0 & 3;
    int row1 = s1 >> 2, kp1 = s1 & 3;
    int po0 = (row0 >> 6) * 68 + (row0 & 63);
    int po1 = (row1 >> 6) * 68 + (row1 & 63);
    short* lb0 = Bs + (size_t)(wave * 64) * 8;
    short* lb1 = Bs + (size_t)(256 + wave * 64) * 8;
    const u16* ibase = Ipad + ((size_t)(b * 68 + y0) * 68) * 512;
    int tap = 0;
    for (int ky = 0; ky < 5; ky++) {
        for (int kx = 0; kx < 5; kx++, tap++) {
            const u16* wsrc = Wt + (size_t)tap * 262144 + (size_t)m0 * 512;
            const u16* isrc = ibase + (size_t)(ky * 68 + kx) * 512;
            const u16* g0 = isrc + (size_t)po0 * 512 + kp0 * 8;
            const u16* g1 = isrc + (size_t)po1 * 512 + kp1 * 8;
            for (int k0 = 0; k0 < 512; k0 += 32) {
                stage128x32(wsrc + k0, 512, As, t);
                gload_lds16((const void*)(g0 + k0), (void*)lb0);
                gload_lds16((const void*)(g1 + k0), (void*)lb1);
                __syncthreads();
                bf16x8 af[4], bfr[4];
#pragma unroll
                for (int i = 0; i < 4; i++) af[i] = *(const bf16x8*)&As[aoff[i]];
#pragma unroll
                for (int j = 0; j < 4; j++) bfr[j] = *(const bf16x8*)&Bs[boff[j]];
#pragma unroll
                for (int i = 0; i < 4; i++)
#pragma unroll
                    for (int j = 0; j < 4; j++)
                        acc[i][j] = __builtin_amdgcn_mfma_f32_16x16x32_bf16(af[i], bfr[j], acc[i][j], 0, 0, 0);
                __syncthreads();
            }
        }
    }
#pragma unroll
    for (int i = 0; i < 4; i++) {
        int ocbase = m0 + wm * 64 + i * 16 + kg * 4;
#pragma unroll
        for (int j = 0; j < 4; j++) {
            int c = wn * 64 + j * 16 + lm;
            int py = y0 + (c >> 6), px = c & 63;
#pragma unroll
            for (int r = 0; r < 4; r++) {
                int oc = ocbase + r;
                out[((size_t)(b * 512 + oc) << 12) + (py << 6) + px] = acc[i][j][r] + bias[oc];
            }
        }
    }
}

// ---------------- patchify (B,512,64,64) f32 -> (B,1024,2048) bf16 ----------------
__global__ void patchify_kernel(const float* __restrict__ hn, u16* __restrict__ pout) {
    int idx = blockIdx.x * 256 + threadIdx.x;
    int kf = idx & 2047;
    int tk = (idx >> 11) & 1023;
    int b = idx >> 21;
    int c = kf >> 2;
    int a = (kf >> 1) & 1;
    int b2 = kf & 1;
    int ph = tk >> 5, pw = tk & 31;
    pout[idx] = f2b(hn[(size_t)((b * 512 + c)) * 4096 + (((ph << 1) + a) << 6) + (pw << 1) + b2]);
}

// ---------------- layernorm + modulate (fp32 in, fp32 or bf16 out) ----------------
template <typename OT>
__global__ __launch_bounds__(256) void ln_mod_kernel(const float* __restrict__ in, OT* __restrict__ out,
                                                     const float* __restrict__ g, const float* __restrict__ bt,
                                                     const float* __restrict__ shiftb, const float* __restrict__ scaleb,
                                                     int modStride, float eps) {
    int row = blockIdx.x;
    int b = row >> 10;
    int t = threadIdx.x;
    const float* p = in + ((size_t)row << 10);
    float4 x = ((const float4*)p)[t];
    float s = x.x + x.y + x.z + x.w;
    float sq = x.x * x.x + x.y * x.y + x.z * x.z + x.w * x.w;
    __shared__ float2 red[256];
    red[t] = make_float2(s, sq);
    __syncthreads();
    for (int st = 128; st > 0; st >>= 1) {
        if (t < st) { red[t].x += red[t + st].x; red[t].y += red[t + st].y; }
        __syncthreads();
    }
    float mean = red[0].x * (1.f / 1024.f);
    float var = red[0].y * (1.f / 1024.f) - mean * mean;
    float rstd = rsqrtf(var + eps);
    const float* sh = shiftb + b * modStride;
    const float* sc = scaleb + b * modStride;
    int c = t << 2;
    float o0, o1, o2, o3;
    {
        float xn = (x.x - mean) * rstd; if (g) xn = xn * g[c + 0] + bt[c + 0];
        o0 = xn * (1.f + sc[c + 0]) + sh[c + 0];
    }
    {
        float xn = (x.y - mean) * rstd; if (g) xn = xn * g[c + 1] + bt[c + 1];
        o1 = xn * (1.f + sc[c + 1]) + sh[c + 1];
    }
    {
        float xn = (x.z - mean) * rstd; if (g) xn = xn * g[c + 2] + bt[c + 2];
        o2 = xn * (1.f + sc[c + 2]) + sh[c + 2];
    }
    {
        float xn = (x.w - mean) * rstd; if (g) xn = xn * g[c + 3] + bt[c + 3];
        o3 = xn * (1.f + sc[c + 3]) + sh[c + 3];
    }
    if constexpr (sizeof(OT) == 4) {
        float4 o = make_float4(o0, o1, o2, o3);
        ((float4*)(out + ((size_t)row << 10)))[t] = o;
    } else {
        ushort4 o;
        o.x = f2b(o0); o.y = f2b(o1); o.z = f2b(o2); o.w = f2b(o3);
        ((ushort4*)(out + ((size_t)row << 10)))[t] = o;
    }
}

// ---------------- rope cos/sin table: (1024 positions x 32 freqs) float2 ----------------
__global__ void rope_table_kernel(float* __restrict__ RT) {
    int idx = blockIdx.x * 256 + threadIdx.x;  // 32768
    int j = idx & 31;
    int tt = idx >> 5;
    float inv = powf(10000.f, -(float)j * (1.f / 32.f));
    float ang = (float)tt * inv;
    ((float2*)RT)[idx] = make_float2(cosf(ang), sinf(ang));
}

// ---------------- V transpose bf16: (B,T,H,D) -> (B,H,D,T), LDS tiled ----------------
__global__ __launch_bounds__(256) void vtrans_kernel(const u16* __restrict__ v, u16* __restrict__ vT) {
    int st = blockIdx.x, h = blockIdx.y, b = blockIdx.z;
    int s0 = st << 6;
    __shared__ u16 tile[64][68];  // pad 4 -> 8B-aligned rows, spread banks
    int t = threadIdx.x;
#pragma unroll
    for (int rep = 0; rep < 4; rep++) {
        int i = rep * 256 + t;       // 0..1023
        int sl = i >> 4, d4 = (i & 15) << 2;
        *(ushort4*)&tile[sl][d4] =
            *(const ushort4*)&v[(size_t)((b << 10) + s0 + sl) * 1024 + (h << 6) + d4];
    }
    __syncthreads();
#pragma unroll
    for (int rep = 0; rep < 4; rep++) {
        int i = rep * 256 + t;
        int d = i >> 4, sl4 = (i & 15) << 2;
        ushort4 o;
        o.x = tile[sl4 + 0][d];
        o.y = tile[sl4 + 1][d];
        o.z = tile[sl4 + 2][d];
        o.w = tile[sl4 + 3][d];
        *(ushort4*)&vT[(size_t)(((b * 16 + h) << 6) + d) * 1024 + s0 + sl4] = o;
    }
}

// ---------------- fused flash attention via MFMA ----------------
// grid (8 q-tiles, 16 h, 4 b), 256 thr = 4 waves x 32 q-rows. K/V-tiles of 128.
__global__ __launch_bounds__(256, 2) void attn_mfma_kernel(
    const u16* __restrict__ q, const u16* __restrict__ k,
    const u16* __restrict__ vT, u16* __restrict__ o) {
    __shared__ __align__(16) short Ks[128 * 64];    // 16 KB [s][d] swizzled
    __shared__ __align__(16) short Vts[64 * 128];   // 16 KB [d][s] swizzled
    __shared__ __align__(16) short Ps[4 * 32 * 128];// 32 KB per-wave [q][s] swizzled
    int t = threadIdx.x;
    int lane = t & 63, wm = t >> 6;
    int lm = lane & 15, kg = lane >> 4;
    int tq0 = blockIdx.x << 7, h = blockIdx.y, b = blockIdx.z;

    const u16* qbase = q + ((size_t)((b << 10) + tq0 + wm * 32)) * 1024 + (h << 6);
    bf16x8 afq[2][2];
#pragma unroll
    for (int i = 0; i < 2; i++)
#pragma unroll
        for (int kk = 0; kk < 2; kk++)
            afq[i][kk] = *(const bf16x8*)(qbase + (size_t)(i * 16 + lm) * 1024 + kk * 32 + kg * 8);

    floatx4 zero4 = {0.f, 0.f, 0.f, 0.f};
    floatx4 oacc[2][4];
    float m_[2][4], l_[2][4];
#pragma unroll
    for (int i = 0; i < 2; i++)
#pragma unroll
        for (int r = 0; r < 4; r++) { m_[i][r] = -3.0e38f; l_[i][r] = 0.f; }
#pragma unroll
    for (int i = 0; i < 2; i++)
#pragma unroll
        for (int jn = 0; jn < 4; jn++) oacc[i][jn] = zero4;

    const u16* kb0 = k + ((size_t)(b << 10)) * 1024 + (h << 6);
    const u16* vb0 = vT + ((size_t)((b * 16 + h) << 6)) * 1024;
    u16* Pw = (u16*)Ps + wm * 4096;

    for (int s0 = 0; s0 < 1024; s0 += 128) {
        stage_attn128x64(kb0 + (size_t)s0 * 1024, Ks, t);
        stage_attn64x128(vb0 + s0, Vts, t);
        __syncthreads();

        // ---- S = Q @ K^T ----
        floatx4 sacc[2][8];
#pragma unroll
        for (int i = 0; i < 2; i++)
#pragma unroll
            for (int j = 0; j < 8; j++) sacc[i][j] = zero4;
        __builtin_amdgcn_s_setprio(1);
#pragma unroll
        for (int j = 0; j < 8; j++) {
            int row = j * 16 + lm;
            bf16x8 bk0 = *(const bf16x8*)&Ks[row * 64 + ((kg ^ (row & 7)) << 3)];
            bf16x8 bk1 = *(const bf16x8*)&Ks[row * 64 + (((4 + kg) ^ (row & 7)) << 3)];
#pragma unroll
            for (int i = 0; i < 2; i++) {
                sacc[i][j] = __builtin_amdgcn_mfma_f32_16x16x32_bf16(afq[i][0], bk0, sacc[i][j], 0, 0, 0);
                sacc[i][j] = __builtin_amdgcn_mfma_f32_16x16x32_bf16(afq[i][1], bk1, sacc[i][j], 0, 0, 0);
            }
        }
        __builtin_amdgcn_s_setprio(0);

        // ---- online softmax (scale 0.125 folded into max/exp) ----
        float al[2][4], ps[2][4];
#pragma unroll
        for (int i = 0; i < 2; i++)
#pragma unroll
            for (int r = 0; r < 4; r++) {
                float v = sacc[i][0][r];
#pragma unroll
                for (int j = 1; j < 8; j++) v = fmaxf(v, sacc[i][j][r]);
                v = fmaxf(v, __shfl_xor(v, 1));
                v = fmaxf(v, __shfl_xor(v, 2));
                v = fmaxf(v, __shfl_xor(v, 4));
                v = fmaxf(v, __shfl_xor(v, 8));
                float mn = fmaxf(m_[i][r], v * 0.125f);
                al[i][r] = __expf(m_[i][r] - mn);
                m_[i][r] = mn;
                l_[i][r] *= al[i][r];
                ps[i][r] = 0.f;
            }
#pragma unroll
        for (int i = 0; i < 2; i++)
#pragma unroll
            for (int jn = 0; jn < 4; jn++)
#pragma unroll
                for (int r = 0; r < 4; r++) oacc[i][jn][r] *= al[i][r];

        // ---- P = exp(S*scale - m), write to per-wave swizzled LDS ----
#pragma unroll
        for (int i = 0; i < 2; i++)
#pragma unroll
            for (int j = 0; j < 8; j++) {
                int s = j * 16 + lm;
                int chunk = s >> 3;
#pragma unroll
                for (int r = 0; r < 4; r++) {
                    int qr = i * 16 + kg * 4 + r;
                    float e = __expf(fmaf(sacc[i][j][r], 0.125f, -m_[i][r]));
                    ps[i][r] += e;
                    int cs = (chunk & 8) | ((chunk ^ qr) & 7);
                    Pw[qr * 128 + cs * 8 + (s & 7)] = f2b(e);
                }
            }
#pragma unroll
        for (int i = 0; i < 2; i++)
#pragma unroll
            for (int r = 0; r < 4; r++) {
                float v = ps[i][r];
                v += __shfl_xor(v, 1);
                v += __shfl_xor(v, 2);
                v += __shfl_xor(v, 4);
                v += __shfl_xor(v, 8);
                l_[i][r] += v;
            }

        // ---- O += P @ V  (A = P [q][s], B = V^T [d][s]) ----
        __builtin_amdgcn_s_setprio(1);
#pragma unroll
        for (int ks = 0; ks < 4; ks++) {
            int chunk = ks * 4 + kg;
            bf16x8 pa[2];
#pragma unroll
            for (int i = 0; i < 2; i++) {
                int qr = i * 16 + lm;
                int cs = (chunk & 8) | ((chunk ^ qr) & 7);
                pa[i] = *(const bf16x8*)&Pw[qr * 128 + cs * 8];
            }
#pragma unroll
            for (int jn = 0; jn < 4; jn++) {
                int row = jn * 16 + lm;
                int cs = (chunk & 8) | ((chunk ^ row) & 7);
                bf16x8 bv = *(const bf16x8*)&Vts[row * 128 + cs * 8];
#pragma unroll
                for (int i = 0; i < 2; i++)
                    oacc[i][jn] = __builtin_amdgcn_mfma_f32_16x16x32_bf16(pa[i], bv, oacc[i][jn], 0, 0, 0);
            }
        }
        __builtin_amdgcn_s_setprio(0);
        __syncthreads();
    }

    // ---- epilogue: O /= l ----
    u16* obase = o + ((size_t)((b << 10) + tq0 + wm * 32)) * 1024 + (h << 6);
#pragma unroll
    for (int i = 0; i < 2; i++)
#pragma unroll
        for (int r = 0; r < 4; r++) {
            float inv = 1.f / l_[i][r];
            int qr = i * 16 + kg * 4 + r;
#pragma unroll
            for (int jn = 0; jn < 4; jn++)
                obase[(size_t)qr * 1024 + jn * 16 + lm] = f2b(oacc[i][jn][r] * inv);
        }
}

// ---------------- small row-vector GEMM (fp32) ----------------
__global__ __launch_bounds__(256) void rowvec_gemm_kernel(const float* __restrict__ A, const float* __restrict__ W,
                                                          const float* __restrict__ bias, float* __restrict__ out,
                                                          int N, int K) {
    int wid = blockIdx.x * 4 + (threadIdx.x >> 6);
    int lane = threadIdx.x & 63;
    int b = wid / N, n = wid - b * N;
    const float* a = A + (size_t)b * K;
    const float* w = W + (size_t)n * K;
    float s = 0.f;
    for (int k = lane << 2; k < K; k += 256) {
        float4 av = *(const float4*)&a[k];
        float4 wv = *(const float4*)&w[k];
        s += av.x * wv.x + av.y * wv.y + av.z * wv.z + av.w * wv.w;
    }
#pragma unroll
    for (int off = 32; off > 0; off >>= 1) s += __shfl_xor(s, off);
    if (lane == 0) out[wid] = s + (bias ? bias[n] : 0.f);
}

// ---------------- final projection: (4096x1024) @ (16x1024)^T + bias (fp32) ----------------
__global__ __launch_bounds__(256) void fin_gemm_kernel(const float* __restrict__ zf, const float* __restrict__ w,
                                                       const float* __restrict__ bias, float* __restrict__ out) {
    int idx = blockIdx.x * 256 + threadIdx.x;  // 65536
    int m = idx >> 4, n = idx & 15;
    const float* a = zf + ((size_t)m << 10);
    const float* wp = w + ((size_t)n << 10);
    float s = 0.f;
    for (int k = 0; k < 1024; k += 4) {
        float4 av = *(const float4*)&a[k];
        float4 wv = *(const float4*)&wp[k];
        s += av.x * wv.x + av.y * wv.y + av.z * wv.z + av.w * wv.w;
    }
    out[idx] = s + bias[n];
}

// ---------------- unpatchify -> (B,4,64,64) ----------------
__global__ void unpatch_kernel(const float* __restrict__ ot, float* __restrict__ out) {
    int idx = blockIdx.x * 256 + threadIdx.x;  // 65536
    int x = idx & 63;
    int yy = (idx >> 6) & 63;
    int ci = (idx >> 12) & 3;
    int b = idx >> 14;
    out[idx] = ot[(size_t)(((b << 10) + ((yy >> 1) << 5) + (x >> 1))) * 16 + (((yy & 1) << 1) + (x & 1)) * 4 + ci];
}

// ---------------- host orchestration ----------------
extern "C" void kernel_launch(void* const* d_in, const int* in_sizes, int n_in,
                              void* d_out, int out_size, void* d_ws, size_t ws_size,
                              hipStream_t stream) {
    const float* x       = (const float*)d_in[0];
    const float* tin     = (const float*)d_in[1];
    const int*   y       = (const int*)d_in[2];
    const float* conv1_w = (const float*)d_in[3];
    const float* conv1_b = (const float*)d_in[4];
    const float* gn1_g   = (const float*)d_in[5];
    const float* gn1_b   = (const float*)d_in[6];
    const float* conv2_w = (const float*)d_in[7];
    const float* conv2_b = (const float*)d_in[8];
    const float* gn2_g   = (const float*)d_in[9];
    const float* gn2_b   = (const float*)d_in[10];
    const float* xemb_w  = (const float*)d_in[11];
    const float* xemb_b  = (const float*)d_in[12];
    const float* t1_w    = (const float*)d_in[13];
    const float* t1_b    = (const float*)d_in[14];
    const float* t2_w    = (const float*)d_in[15];
    const float* t2_b    = (const float*)d_in[16];
    const float* y_emb   = (const float*)d_in[17];
    const float* wq      = (const float*)d_in[18];
    const float* wk      = (const float*)d_in[19];
    const float* wv      = (const float*)d_in[20];
    const float* wo      = (const float*)d_in[21];
    const float* w1      = (const float*)d_in[22];
    const float* w3      = (const float*)d_in[23];   // dict order: w1, w3, w2
    const float* w2      = (const float*)d_in[24];
    const float* ada_w   = (const float*)d_in[25];
    const float* ada_b   = (const float*)d_in[26];
    const float* an_g    = (const float*)d_in[27];
    const float* an_b    = (const float*)d_in[28];
    const float* fn_g    = (const float*)d_in[29];
    const float* fn_b    = (const float*)d_in[30];
    const float* fin_ada_w = (const float*)d_in[31];
    const float* fin_ada_b = (const float*)d_in[32];
    const float* fin_w   = (const float*)d_in[33];
    const float* fin_b   = (const float*)d_in[34];

    char* wsb = (char*)d_ws;
    float* Z    = (float*)(wsb + 0);               // 16 MB residual stream (fp32)
    u16*  Wbf   = (u16*)(wsb + (16ull << 20));     // 18 MB per-layer bf16 weights
    u16*  HHb   = (u16*)(wsb + (34ull << 20));     // 8 MB ln/mod output bf16
    u16*  Qb    = (u16*)(wsb + (42ull << 20));     // 8 MB
    u16*  Kb    = (u16*)(wsb + (50ull << 20));     // 8 MB
    u16*  Vb    = (u16*)(wsb + (58ull << 20));     // 8 MB
    u16*  VTb   = (u16*)(wsb + (66ull << 20));     // 8 MB V transposed (B,H,D,T)
    u16*  AOb   = (u16*)(wsb + (74ull << 20));     // 8 MB attn out bf16
    u16*  F1b   = (u16*)(wsb + (82ull << 20));     // 23.1 MB ff hidden bf16
    // stem-phase overlays (dead once the transformer starts)
    float* A0f  = (float*)(wsb + (42ull << 20));   // 33.6 MB
    float* A1f  = (float*)(wsb + (76ull << 20));   // 33.6 MB
    u16*  IPad  = (u16*)(wsb + 0);                 // 18.1 MB padded NHWC bf16 (overlays Z)
    u16*  WTc   = (u16*)(wsb + (20ull << 20));     // 12.5 MB conv2 tap-major bf16 weights
    u16*  PATb  = (u16*)(wsb + (16ull << 20));     // 16.8 MB patches bf16
    u16*  XWb   = (u16*)(wsb + (34ull << 20));     // 4 MB xemb_w bf16
    float* ZF   = (float*)(wsb + (42ull << 20));   // final zf fp32 (over Qb/Kb)
    float* SM   = (float*)(wsb + (110ull << 20));  // small buffers
    float* TMB  = SM;            // 4096
    float* CSI  = TMB + 4096;    // 4096
    float* MODS = CSI + 4096;    // 24576
    float* FM   = MODS + 24576;  // 8192
    float* OT   = FM + 8192;     // 65536
    float* RT   = (float*)(wsb + (112ull << 20));  // 256 KB rope table

    // constant prep (no activation deps)
    hipMemsetAsync(IPad, 0, (size_t)4 * 68 * 68 * 512 * 2, stream);
    rope_table_kernel<<<128, 256, 0, stream>>>(RT);
    wtrans25_kernel<<<1024, 256, 0, stream>>>(conv2_w, WTc);

    // conditioning
    temb1_kernel<<<16, 256, 0, stream>>>(tin, t1_w, t1_b, TMB);
    temb2_kernel<<<1024, 256, 0, stream>>>(TMB, t2_w, t2_b, y_emb, y, CSI);

    // conv stem
    conv1_kernel<<<32768, 256, 0, stream>>>(x, conv1_w, conv1_b, A0f);
    silu_gn_kernel<<<128, 256, 0, stream>>>(A0f, A1f, gn1_g, gn1_b);
    nchw2nhwc_pad_kernel<<<4096, 256, 0, stream>>>(A1f, IPad);
    conv2_mfma_kernel<<<dim3(128, 4), 256, 0, stream>>>(IPad, WTc, conv2_b, A0f);
    silu_gn_kernel<<<128, 256, 0, stream>>>(A0f, A1f, gn2_g, gn2_b);
    patchify_kernel<<<32768, 256, 0, stream>>>(A1f, PATb);
    f2bN_kernel<<<2048, 256, 0, stream>>>(xemb_w, nullptr, nullptr, nullptr, XWb, 524288, 1);
    mfma_gemm64_kernel<<<dim3(16, 32), 256, 0, stream>>>(PATb, XWb, 4096, 1024, 2048,
                                                         Z, xemb_b, nullptr, nullptr, 0);

    for (int i = 0; i < NLAYERS; i++) {
        const float* wq_i = wq + (size_t)i * 1048576;
        const float* wk_i = wk + (size_t)i * 1048576;
        const float* wv_i = wv + (size_t)i * 1048576;
        const float* wo_i = wo + (size_t)i * 1048576;
        const float* w1_i = w1 + (size_t)i * 2883584;
        const float* w3_i = w3 + (size_t)i * 2883584;
        const float* w2_i = w2 + (size_t)i * 2883584;
        const float* ada_w_i = ada_w + (size_t)i * 6291456;
        const float* ada_b_i = ada_b + (size_t)i * 6144;

        // bf16 weights for attn part: [wq|wk|wv|wo] (rows 0..3071 = fused QKV)
        f2bN_kernel<<<4096, 256, 0, stream>>>(wq_i, wk_i, wv_i, wo_i, Wbf, 262144, 4);
        // adaLN mods (fp32)
        rowvec_gemm_kernel<<<6144, 256, 0, stream>>>(CSI, ada_w_i, ada_b_i, MODS, 6144, 1024);
        // attn branch
        ln_mod_kernel<u16><<<4096, 256, 0, stream>>>(Z, HHb, an_g + i * 1024, an_b + i * 1024,
                                                     MODS + 0, MODS + 1024, 6144, 1e-5f);
        mfma_qkv_kernel<<<dim3(24, 32), 256, 0, stream>>>(HHb, Wbf, RT, Qb, Kb, Vb);
        vtrans_kernel<<<dim3(16, 16, 4), 256, 0, stream>>>(Vb, VTb);
        attn_mfma_kernel<<<dim3(8, 16, 4), 256, 0, stream>>>(Qb, Kb, VTb, AOb);
        mfma_gemm64_kernel<<<dim3(16, 32), 256, 0, stream>>>(AOb, Wbf + 3145728ull, 4096, 1024, 1024,
                                                             nullptr, nullptr, Z, MODS + 2048, 6144);
        // ff branch
        ln_mod_kernel<u16><<<4096, 256, 0, stream>>>(Z, HHb, fn_g + i * 1024, fn_b + i * 1024,
                                                     MODS + 3072, MODS + 4096, 6144, 1e-5f);
        f2bN_kernel<<<8448, 256, 0, stream>>>(w1_i, w3_i, w2_i, nullptr, Wbf, 720896, 3);
        mfma_gemm_swiglu_kernel<<<dim3(22, 32), 256, 0, stream>>>(HHb, Wbf, Wbf + 2883584ull,
                                                                  4096, 2816, 1024, F1b);
        mfma_gemm64_kernel<<<dim3(16, 32), 256, 0, stream>>>(F1b, Wbf + 5767168ull, 4096, 1024, 2816,
                                                             nullptr, nullptr, Z, MODS + 5120, 6144);
    }

    // final head
    rowvec_gemm_kernel<<<2048, 256, 0, stream>>>(CSI, fin_ada_w, fin_ada_b, FM, 2048, 1024);
    ln_mod_kernel<float><<<4096, 256, 0, stream>>>(Z, ZF, nullptr, nullptr, FM + 0, FM + 1024, 2048, 1e-6f);
    fin_gemm_kernel<<<256, 256, 0, stream>>>(ZF, fin_w, fin_b, OT);
    unpatch_kernel<<<256, 256, 0, stream>>>(OT, (float*)d_out);
}